// Round 10
// baseline (992.507 us; speedup 1.0000x reference)
//
#include <hip/hip_runtime.h>
#include <hip/hip_bf16.h>
#include <math.h>

#define T_SEQ 2048
#define DM 1024
#define NH 16
#define DH 64
#define CHUNK 64
#define NCHUNK (T_SEQ / CHUNK)   // 32
#define NBLK 512                 // 2 blocks/CU on 256 CUs; co-residency by construction
#define PREP_UNITS (T_SEQ + 5 * DM * DM / 4 / 256)   // 7168

typedef __hip_bfloat16 bf16;
typedef __attribute__((ext_vector_type(8))) short short8;
typedef __attribute__((ext_vector_type(4))) short short4v;
typedef __attribute__((ext_vector_type(4))) float f32x4;

static __device__ __forceinline__ short f2b_bits(float f) {
  bf16 t = __float2bfloat16(f);
  short s;
  __builtin_memcpy(&s, &t, 2);
  return s;
}
static __device__ __forceinline__ float b2f(short s) {
  unsigned int u = ((unsigned int)(unsigned short)s) << 16;
  float f;
  __builtin_memcpy(&f, &u, 4);
  return f;
}
static __device__ __forceinline__ float gelu1(float raw, float gate, float inv) {
  float x = raw * gate * inv;
  return x > 0.f ? x + 1.f : __expf(x);
}
static __device__ __forceinline__ void gload16(const void* g, void* l) {
  __builtin_amdgcn_global_load_lds((const __attribute__((address_space(1))) void*)g,
                                   (__attribute__((address_space(3))) void*)l, 16, 0, 0);
}

// Software grid barrier (graph-capturable, unlike cooperative launch — R18's
// failure mode). All threads release-fence their writes, block-leader does a
// device-scope ACQ_REL increment and spins on AGENT-scope acquire loads;
// acquire fence after. Co-residency of all 512 blocks is guaranteed by
// resource arithmetic (93.7 KB LDS / CU for 2 blocks; launch_bounds(256,2)).
static __device__ __forceinline__ void gbar(int* cnt, int tid) {
  __threadfence();            // release: flush this thread's global writes
  __syncthreads();
  if (tid == 0) {
    __hip_atomic_fetch_add(cnt, 1, __ATOMIC_ACQ_REL, __HIP_MEMORY_SCOPE_AGENT);
    while (__hip_atomic_load(cnt, __ATOMIC_ACQUIRE, __HIP_MEMORY_SCOPE_AGENT) < NBLK)
      __builtin_amdgcn_s_sleep(2);
  }
  __syncthreads();
  __threadfence();            // acquire: invalidate stale cached lines
}

struct MegaArgs {
  const float *x, *ln_g, *ln_b, *qkv_w, *qkv_b, *gate_w, *gate_b, *proj_w, *proj_b;
  bf16 *xn, *xbf, *wqkv, *wgate, *wproj;
  short *Gb;
  float *gate_accum;
  short *Qb, *Kb, *Vb, *VbT;
  bf16 *Obuf;
  float *SkvT, *Sk;
  float *out;
  int *cnt;   // 5 phase counters, memset to 0 on stream before launch
};

// ---------------------------------------------------------------------------
// R21: persistent mega-kernel, phase bodies = R19's verbatim (passing,
// 161.9us as 6 kernels). Software gbar() at the 5 phase boundaries replaces
// both kernel launches and R18's non-capturable grid.sync().
// LDS arena 46848 B = max(gemm 32K, chunk 34816, attn 46848, proj 16K).
// ---------------------------------------------------------------------------
__global__ __launch_bounds__(256, 2) void mega_kernel(MegaArgs a) {
  __shared__ __align__(16) char smem[46848];
  const int b = blockIdx.x;
  const int tid = threadIdx.x;

  // ============================ phase 0: prep ==============================
  {
    float* red = (float*)smem;
    for (int u = b; u < PREP_UNITS; u += NBLK) {
      if (u < T_SEQ) {
        const int row = u;
        if (row < 8) a.gate_accum[row * 256 + tid] = 0.f;
        const float* xr = a.x + (size_t)row * DM;
        float vals[4];
        float s = 0.f, s2 = 0.f;
#pragma unroll
        for (int i = 0; i < 4; i++) {
          float v = xr[tid + i * 256];
          vals[i] = v;
          s += v;
          s2 += v * v;
        }
#pragma unroll
        for (int m = 1; m < 64; m <<= 1) {
          s += __shfl_xor(s, m, 64);
          s2 += __shfl_xor(s2, m, 64);
        }
        const int wid = tid >> 6;
        if ((tid & 63) == 0) {
          red[wid] = s;
          red[4 + wid] = s2;
        }
        __syncthreads();
        s = red[0] + red[1] + red[2] + red[3];
        s2 = red[4] + red[5] + red[6] + red[7];
        const float mean = s * (1.f / DM);
        const float var = s2 * (1.f / DM) - mean * mean;
        const float rstd = rsqrtf(var + 1e-5f);
#pragma unroll
        for (int i = 0; i < 4; i++) {
          int idx = tid + i * 256;
          float v = (vals[i] - mean) * rstd * a.ln_g[idx] + a.ln_b[idx];
          a.xn[(size_t)row * DM + idx] = __float2bfloat16(v);
          a.xbf[(size_t)row * DM + idx] = __float2bfloat16(vals[i]);
        }
        __syncthreads();   // red[] reused by next grid-stride unit
      } else {
        constexpr int NQ = 3 * DM * DM / 4, NS = DM * DM / 4;
        int i = (u - T_SEQ) * 256 + tid;
        const float* src;
        bf16* dst;
        int j;
        if (i < NQ) { src = a.qkv_w; dst = a.wqkv; j = i; }
        else if (i < NQ + NS) { src = a.gate_w; dst = a.wgate; j = i - NQ; }
        else { src = a.proj_w; dst = a.wproj; j = i - NQ - NS; }
        float4 v = ((const float4*)src)[j];
        short4v sv;
        sv.x = f2b_bits(v.x); sv.y = f2b_bits(v.y);
        sv.z = f2b_bits(v.z); sv.w = f2b_bits(v.w);
        *(short4v*)&dst[j * 4] = sv;
      }
    }
  }
  gbar(&a.cnt[0], tid);

  // ======================= phase 1: gate+qkv GEMM ==========================
  // R19/R15 body: 128x128 tile, BK=64, wave 64x64, acc[4][4], XOR swizzle.
  {
    constexpr int K = 1024;
    short* As = (short*)smem;             // 16 KB
    short* Bs = (short*)(smem + 16384);   // 16 KB

    const int wid = tid >> 6, lane = tid & 63;
    const int wm = wid >> 1, wn = wid & 1;
    const int lm = lane & 15, quad = lane >> 4;

    const int nt = b & 31;
    const bool isGate = nt < 8;
    const int m0 = (b >> 5) * 128;
    const int n0 = (isGate ? nt : nt - 8) * 128;
    const short* Ag = (const short*)(isGate ? a.xbf : a.xn);
    const short* Wg = (const short*)(isGate ? a.wgate : a.wqkv);

    f32x4 zero = {0.f, 0.f, 0.f, 0.f};
    f32x4 acc[4][4];
#pragma unroll
    for (int i = 0; i < 4; i++)
#pragma unroll
      for (int j = 0; j < 4; j++) acc[i][j] = zero;

    const int grow = tid >> 3;
    const int swq = ((tid & 7) ^ ((tid >> 3) & 7)) * 8;

    for (int kb = 0; kb < K; kb += 64) {
      __syncthreads();
#pragma unroll
      for (int it = 0; it < 4; it++) {
        const int row = it * 32 + grow;
        gload16(&Ag[(size_t)(m0 + row) * K + kb + swq], &As[it * 2048 + wid * 512]);
        gload16(&Wg[(size_t)(n0 + row) * K + kb + swq], &Bs[it * 2048 + wid * 512]);
      }
      __syncthreads();
#pragma unroll
      for (int sec = 0; sec < 2; sec++) {
        const int slot8 = (((sec * 4 + quad) ^ (lm & 7)) * 8);
        short8 afr[4], bfr[4];
#pragma unroll
        for (int i = 0; i < 4; i++)
          afr[i] = *(const short8*)&As[(wm * 64 + i * 16 + lm) * 64 + slot8];
#pragma unroll
        for (int j = 0; j < 4; j++)
          bfr[j] = *(const short8*)&Bs[(wn * 64 + j * 16 + lm) * 64 + slot8];
#pragma unroll
        for (int i = 0; i < 4; i++)
#pragma unroll
          for (int j = 0; j < 4; j++)
            acc[i][j] = __builtin_amdgcn_mfma_f32_16x16x32_bf16(afr[i], bfr[j], acc[i][j], 0, 0, 0);
      }
    }

    if (isGate) {
      float* red = (float*)smem;
      __syncthreads();
#pragma unroll
      for (int i = 0; i < 4; i++) {
#pragma unroll
        for (int r = 0; r < 4; r++) {
          const int rowl = wm * 64 + i * 16 + quad * 4 + r;
          const int row = m0 + rowl;
          float rp = 0.f;
#pragma unroll
          for (int j = 0; j < 4; j++) {
            const int col = n0 + wn * 64 + j * 16 + lm;
            float v = acc[i][j][r] + a.gate_b[col];
            float sig = 1.f / (1.f + __expf(-v));
            a.Gb[(size_t)row * DM + col] = f2b_bits(sig);
            rp += sig;
          }
          red[rowl * 32 + wn * 16 + lm] = rp;
        }
      }
      __syncthreads();
      if (tid < 128) {
        float s = 0.f;
#pragma unroll
        for (int t2 = 0; t2 < 32; t2++) s += red[tid * 32 + t2];
        atomicAdd(&a.gate_accum[m0 + tid], s);
      }
    } else {
#pragma unroll
      for (int i = 0; i < 4; i++) {
        const int rbase = m0 + wm * 64 + i * 16 + quad * 4;
#pragma unroll
        for (int j = 0; j < 4; j++) {
          const int col = n0 + wn * 64 + j * 16 + lm;
          const float bval = a.qkv_b[col];
#pragma unroll
          for (int r = 0; r < 4; r++) {
            const int row = rbase + r;
            const short bv = f2b_bits(acc[i][j][r] + bval);
            if (col < DM) {
              const int d = col;
              a.Qb[((size_t)(d >> 6) * T_SEQ + row) * DH + (d & 63)] = bv;
            } else if (col < 2 * DM) {
              const int d = col - DM;
              a.Kb[((size_t)(d >> 6) * T_SEQ + row) * DH + (d & 63)] = bv;
            } else {
              const int d = col - 2 * DM;
              a.Vb[((size_t)(d >> 6) * T_SEQ + row) * DH + (d & 63)] = bv;
              a.VbT[((size_t)(d >> 6) * DH + (d & 63)) * T_SEQ + row] = bv;
            }
          }
        }
      }
    }
  }
  gbar(&a.cnt[1], tid);

  // ========================= phase 2: chunk sums ===========================
  {
    constexpr int STR = 68;
    float* Ks2 = (float*)smem;             // 17408 B
    float* Vs2 = (float*)(smem + 17408);   // 17408 B
    const int h = b >> 5, c = b & 31;
    const int ty = tid >> 4, tx = tid & 15;
    const int d0 = ty * 4, m0 = tx * 4;
    const int t0 = c * CHUNK;
    const size_t cb = ((size_t)h * T_SEQ + t0) * DH;
#pragma unroll
    for (int p = 0; p < 2; p++) {
      const int f = p * 256 + tid, row = f >> 3, seg = (f & 7) * 8;
      const int t = t0 + row;
      short8 kr = *(const short8*)&a.Kb[cb + row * 64 + seg];
      short8 gr = *(const short8*)&a.Gb[(size_t)t * DM + h * 64 + seg];
      short8 vr = *(const short8*)&a.Vb[cb + row * 64 + seg];
      const float inv = 1.f / (a.gate_accum[t] * (1.f / DM) + 1e-5f);
      f32x4 kg0, kg1, vv0, vv1;
#pragma unroll
      for (int e = 0; e < 4; e++) {
        kg0[e] = gelu1(b2f(kr[e]), b2f(gr[e]), inv);
        kg1[e] = gelu1(b2f(kr[4 + e]), b2f(gr[4 + e]), inv);
        vv0[e] = b2f(vr[e]);
        vv1[e] = b2f(vr[4 + e]);
      }
      *(f32x4*)&Ks2[row * STR + seg] = kg0;
      *(f32x4*)&Ks2[row * STR + seg + 4] = kg1;
      *(f32x4*)&Vs2[row * STR + seg] = vv0;
      *(f32x4*)&Vs2[row * STR + seg + 4] = vv1;
    }
    __syncthreads();
    float acc[4][4] = {};
#pragma unroll 4
    for (int s = 0; s < 64; s++) {
      f32x4 kf = *(const f32x4*)&Ks2[s * STR + d0];
      f32x4 vf = *(const f32x4*)&Vs2[s * STR + m0];
#pragma unroll
      for (int i = 0; i < 4; i++)
#pragma unroll
        for (int j = 0; j < 4; j++) acc[i][j] += kf[i] * vf[j];
    }
    float* outp = a.SkvT + (size_t)b * 4096;
#pragma unroll
    for (int i = 0; i < 4; i++)
#pragma unroll
      for (int j = 0; j < 4; j++)
        outp[(m0 + j) * 64 + (d0 + i)] = acc[i][j];
    if (tid < 64) {
      float ss = 0.f;
#pragma unroll 4
      for (int s = 0; s < 64; s++) ss += Ks2[s * STR + tid];
      a.Sk[b * 64 + tid] = ss;
    }
  }
  gbar(&a.cnt[2], tid);

  // ====================== phase 3: exclusive scan ==========================
  {
    if (b < 256) {
      const int id = b * 256 + tid;
      const int h = id >> 12, e = id & 4095;
      float* base = a.SkvT + (size_t)h * NCHUNK * 4096 + e;
      float v[NCHUNK];
#pragma unroll
      for (int c = 0; c < NCHUNK; c++) v[c] = base[(size_t)c * 4096];
      float run = 0.f;
#pragma unroll
      for (int c = 0; c < NCHUNK; c++) {
        float t = v[c];
        base[(size_t)c * 4096] = run;
        run += t;
      }
    } else if (b < 260) {
      const int id = (b - 256) * 256 + tid;
      const int h = id >> 6, e = id & 63;
      float* base = a.Sk + (size_t)h * NCHUNK * 64 + e;
      float v[NCHUNK];
#pragma unroll
      for (int c = 0; c < NCHUNK; c++) v[c] = base[c * 64];
      float run = 0.f;
#pragma unroll
      for (int c = 0; c < NCHUNK; c++) {
        float t = v[c];
        base[c * 64] = run;
        run += t;
      }
    }
  }
  gbar(&a.cnt[3], tid);

  // ========================== phase 4: attention ===========================
  {
    constexpr int STR = 72;
    short* Qs = (short*)smem;              // 9216 B each
    short* Ks = (short*)(smem + 9216);
    short* Vt = (short*)(smem + 18432);
    short* Pt = (short*)(smem + 27648);
    short* SL = (short*)(smem + 36864);
    float* denp = (float*)(smem + 46080);
    float* invden = (float*)(smem + 46336);
    float* skp = (float*)(smem + 46592);
    const int h = b >> 5, c = b & 31;
    const int wid = tid >> 6, lane = tid & 63;
    const int lm = lane & 15, quad = lane >> 4;
    const int t0 = c * CHUNK;
    const size_t cb = ((size_t)h * T_SEQ + t0) * DH;
    const float* Pg = a.SkvT + (size_t)b * 4096;

#pragma unroll
    for (int p = 0; p < 2; p++) {
      const int f = p * 256 + tid, row = f >> 3, seg = (f & 7) * 8;
      const int t = t0 + row;
      short8 qr = *(const short8*)&a.Qb[cb + row * 64 + seg];
      short8 kr = *(const short8*)&a.Kb[cb + row * 64 + seg];
      short8 gr = *(const short8*)&a.Gb[(size_t)t * DM + h * 64 + seg];
      short8 vtr = *(const short8*)&a.VbT[((size_t)h * DH + row) * T_SEQ + t0 + seg];
      f32x4 pr0 = *(const f32x4*)&Pg[row * 64 + seg];
      f32x4 pr1 = *(const f32x4*)&Pg[row * 64 + seg + 4];
      const float inv = 1.f / (a.gate_accum[t] * (1.f / DM) + 1e-5f);
      short8 qs, ks, ps;
#pragma unroll
      for (int e = 0; e < 8; e++) {
        qs[e] = f2b_bits(gelu1(b2f(qr[e]), b2f(gr[e]), inv));
        ks[e] = f2b_bits(gelu1(b2f(kr[e]), b2f(gr[e]), inv));
      }
#pragma unroll
      for (int e = 0; e < 4; e++) {
        ps[e] = f2b_bits(pr0[e]);
        ps[4 + e] = f2b_bits(pr1[e]);
      }
      *(short8*)&Qs[row * STR + seg] = qs;
      *(short8*)&Ks[row * STR + seg] = ks;
      *(short8*)&Vt[row * STR + seg] = vtr;
      *(short8*)&Pt[row * STR + seg] = ps;
    }
    if (tid < 64) skp[tid] = a.Sk[b * 64 + tid];
    __syncthreads();  // B1

    f32x4 zero = {0.f, 0.f, 0.f, 0.f};
    short8 aq[2];
#pragma unroll
    for (int ks = 0; ks < 2; ks++)
      aq[ks] = *(const short8*)&Qs[(wid * 16 + lm) * STR + ks * 32 + quad * 8];
    f32x4 accs[4];
#pragma unroll
    for (int j = 0; j < 4; j++) accs[j] = zero;
#pragma unroll
    for (int j = 0; j < 4; j++)
#pragma unroll
      for (int ks = 0; ks < 2; ks++) {
        short8 bk = *(const short8*)&Ks[(j * 16 + lm) * STR + ks * 32 + quad * 8];
        accs[j] = __builtin_amdgcn_mfma_f32_16x16x32_bf16(aq[ks], bk, accs[j], 0, 0, 0);
      }
    float rowpart[4] = {0.f, 0.f, 0.f, 0.f};
#pragma unroll
    for (int j = 0; j < 4; j++) {
      const int s = j * 16 + lm;
#pragma unroll
      for (int r = 0; r < 4; r++) {
        const int t = wid * 16 + quad * 4 + r;
        float v = (s <= t) ? accs[j][r] : 0.f;
        accs[j][r] = v;
        rowpart[r] += v;
      }
    }
#pragma unroll
    for (int msk = 1; msk < 16; msk <<= 1)
#pragma unroll
      for (int r = 0; r < 4; r++) rowpart[r] += __shfl_xor(rowpart[r], msk, 64);
    if (lm == 0)
#pragma unroll
      for (int r = 0; r < 4; r++) denp[wid * 16 + quad * 4 + r] = rowpart[r];
#pragma unroll
    for (int j = 0; j < 4; j++)
#pragma unroll
      for (int r = 0; r < 4; r++)
        SL[(wid * 16 + quad * 4 + r) * STR + j * 16 + lm] = f2b_bits(accs[j][r]);

    f32x4 acco[4];
#pragma unroll
    for (int j = 0; j < 4; j++) acco[j] = zero;
    short8 ap[2];
#pragma unroll
    for (int ks = 0; ks < 2; ks++)
      ap[ks] = *(const short8*)&Pt[(wid * 16 + lm) * STR + ks * 32 + quad * 8];
#pragma unroll
    for (int j = 0; j < 4; j++)
#pragma unroll
      for (int ks = 0; ks < 2; ks++) {
        short8 bq = *(const short8*)&Qs[(j * 16 + lm) * STR + ks * 32 + quad * 8];
        acco[j] = __builtin_amdgcn_mfma_f32_16x16x32_bf16(ap[ks], bq, acco[j], 0, 0, 0);
      }
    __syncthreads();  // B2

    {
      const int row = tid >> 2, part = tid & 3;
      float s = 0.f;
#pragma unroll
      for (int dd = 0; dd < 16; dd++) {
        const int d = part * 16 + dd;
        s += b2f(Qs[row * STR + d]) * skp[d];
      }
      s += __shfl_xor(s, 1, 64);
      s += __shfl_xor(s, 2, 64);
      if (part == 0) invden[row] = 1.f / (1e-5f + denp[row] + s);
    }

    short8 av[2];
#pragma unroll
    for (int ks = 0; ks < 2; ks++)
      av[ks] = *(const short8*)&Vt[(wid * 16 + lm) * STR + ks * 32 + quad * 8];
#pragma unroll
    for (int j = 0; j < 4; j++)
#pragma unroll
      for (int ks = 0; ks < 2; ks++) {
        short8 bs = *(const short8*)&SL[(j * 16 + lm) * STR + ks * 32 + quad * 8];
        acco[j] = __builtin_amdgcn_mfma_f32_16x16x32_bf16(av[ks], bs, acco[j], 0, 0, 0);
      }
    __syncthreads();  // B3

#pragma unroll
    for (int j = 0; j < 4; j++) {
      const int t = j * 16 + lm;
      const float idv = invden[t];
      short4v ov;
#pragma unroll
      for (int r = 0; r < 4; r++) ov[r] = f2b_bits(acco[j][r] * idv);
      *(short4v*)&((short*)a.Obuf)[(size_t)(t0 + t) * DM + h * 64 + wid * 16 + quad * 4] = ov;
    }
  }
  gbar(&a.cnt[4], tid);

  // =========================== phase 5: proj ===============================
  {
    constexpr int K = 1024;
    short* As = (short*)smem;            // 8 KB
    short* Bs = (short*)(smem + 8192);   // 8 KB

    const int wid = tid >> 6, lane = tid & 63;
    const int wm = wid >> 1, wn = wid & 1;
    const int lm = lane & 15, quad = lane >> 4;

    const int n0 = (b & 15) * 64;
    const int m0 = (b >> 4) * 64;
    const short* Ag = (const short*)a.Obuf;
    const short* Wg = (const short*)a.wproj;

    const int arow = tid >> 2;
    const int swq = ((tid & 3) ^ ((tid >> 3) & 3)) * 8;
    const int rq8 = (quad ^ ((lm >> 1) & 3)) * 8;

    f32x4 zero = {0.f, 0.f, 0.f, 0.f};
    f32x4 acc[2][2];
#pragma unroll
    for (int i = 0; i < 2; i++)
#pragma unroll
      for (int j = 0; j < 2; j++) acc[i][j] = zero;

    for (int kb = 0; kb < K; kb += 64) {
      __syncthreads();
#pragma unroll
      for (int sec = 0; sec < 2; sec++) {
        gload16(&Ag[(size_t)(m0 + arow) * K + kb + sec * 32 + swq],
                &As[sec * 2048 + wid * 512]);
        gload16(&Wg[(size_t)(n0 + arow) * K + kb + sec * 32 + swq],
                &Bs[sec * 2048 + wid * 512]);
      }
      __syncthreads();
#pragma unroll
      for (int sec = 0; sec < 2; sec++) {
        short8 afr[2], bfr[2];
#pragma unroll
        for (int i = 0; i < 2; i++)
          afr[i] = *(const short8*)&As[sec * 2048 + (wm * 32 + i * 16 + lm) * 32 + rq8];
#pragma unroll
        for (int j = 0; j < 2; j++)
          bfr[j] = *(const short8*)&Bs[sec * 2048 + (wn * 32 + j * 16 + lm) * 32 + rq8];
#pragma unroll
        for (int i = 0; i < 2; i++)
#pragma unroll
          for (int j = 0; j < 2; j++)
            acc[i][j] = __builtin_amdgcn_mfma_f32_16x16x32_bf16(afr[i], bfr[j], acc[i][j], 0, 0, 0);
      }
    }
#pragma unroll
    for (int i = 0; i < 2; i++) {
      const int rbase = m0 + wm * 32 + i * 16 + quad * 4;
#pragma unroll
      for (int j = 0; j < 2; j++) {
        const int col = n0 + wn * 32 + j * 16 + lm;
        const float bval = a.proj_b[col];
#pragma unroll
        for (int r = 0; r < 4; r++)
          a.out[(size_t)(rbase + r) * DM + col] = acc[i][j][r] + bval;
      }
    }
  }
}

// ---------------------------------------------------------------------------
extern "C" void kernel_launch(void* const* d_in, const int* in_sizes, int n_in,
                              void* d_out, int out_size, void* d_ws, size_t ws_size,
                              hipStream_t stream) {
  (void)in_sizes; (void)n_in; (void)out_size; (void)ws_size;
  char* ws = (char*)d_ws;
  size_t off = 0;
  auto alloc = [&](size_t bytes) {
    void* p = ws + off;
    off += (bytes + 255) & ~(size_t)255;
    return p;
  };
  MegaArgs a;
  a.x      = (const float*)d_in[0];
  a.ln_g   = (const float*)d_in[1];
  a.ln_b   = (const float*)d_in[2];
  a.qkv_w  = (const float*)d_in[3];
  a.qkv_b  = (const float*)d_in[4];
  a.gate_w = (const float*)d_in[5];
  a.gate_b = (const float*)d_in[6];
  a.proj_w = (const float*)d_in[7];
  a.proj_b = (const float*)d_in[8];
  a.out    = (float*)d_out;

  a.xn    = (bf16*)alloc((size_t)T_SEQ * DM * 2);
  a.xbf   = (bf16*)alloc((size_t)T_SEQ * DM * 2);
  a.wqkv  = (bf16*)alloc((size_t)3 * DM * DM * 2);
  a.wgate = (bf16*)alloc((size_t)DM * DM * 2);
  a.wproj = (bf16*)alloc((size_t)DM * DM * 2);
  a.Gb    = (short*)alloc((size_t)T_SEQ * DM * 2);
  a.gate_accum = (float*)alloc((size_t)T_SEQ * 4);
  a.Qb    = (short*)alloc((size_t)T_SEQ * DM * 2);
  a.Kb    = (short*)alloc((size_t)T_SEQ * DM * 2);
  a.Vb    = (short*)alloc((size_t)T_SEQ * DM * 2);
  a.VbT   = (short*)alloc((size_t)T_SEQ * DM * 2);
  a.Obuf  = (bf16*)alloc((size_t)T_SEQ * DM * 2);
  a.SkvT  = (float*)alloc((size_t)NH * NCHUNK * 4096 * 4);
  a.Sk    = (float*)alloc((size_t)NH * NCHUNK * 64 * 4);
  a.cnt   = (int*)alloc(8 * sizeof(int));

  hipMemsetAsync(a.cnt, 0, 8 * sizeof(int), stream);
  mega_kernel<<<dim3(NBLK), dim3(256), 0, stream>>>(a);
}

// Round 11
// 159.535 us; speedup vs baseline: 6.2212x; 6.2212x over previous
//
#include <hip/hip_runtime.h>
#include <hip/hip_bf16.h>
#include <math.h>

#define T_SEQ 2048
#define DM 1024
#define NH 16
#define DH 64
#define CHUNK 64
#define NCHUNK (T_SEQ / CHUNK)   // 32

typedef __hip_bfloat16 bf16;
typedef __attribute__((ext_vector_type(8))) short short8;
typedef __attribute__((ext_vector_type(4))) short short4v;
typedef __attribute__((ext_vector_type(4))) float f32x4;

static __device__ __forceinline__ short f2b_bits(float f) {
  bf16 t = __float2bfloat16(f);
  short s;
  __builtin_memcpy(&s, &t, 2);
  return s;
}
static __device__ __forceinline__ float b2f(short s) {
  unsigned int u = ((unsigned int)(unsigned short)s) << 16;
  float f;
  __builtin_memcpy(&f, &u, 4);
  return f;
}
// gated ELU+1: elu(x)+1 = x>0 ? x+1 : exp(x)
static __device__ __forceinline__ float gelu1(float raw, float gate, float inv) {
  float x = raw * gate * inv;
  return x > 0.f ? x + 1.f : __expf(x);
}
static __device__ __forceinline__ void gload16(const void* g, void* l) {
  __builtin_amdgcn_global_load_lds((const __attribute__((address_space(1))) void*)g,
                                   (__attribute__((address_space(3))) void*)l, 16, 0, 0);
}

// ---------------------------------------------------------------------------
// prep: blocks 0..2047 = LayerNorm rows (blocks 0..7 also zero gate_accum);
//       blocks 2048..  = fp32->bf16 weight conversion (qkv|gate|proj).
// ---------------------------------------------------------------------------
#define PREP_WBLOCKS (5 * DM * DM / 4 / 256)   // 5120
__global__ __launch_bounds__(256) void prep_kernel(
    const float* __restrict__ x, const float* __restrict__ g,
    const float* __restrict__ b, const float* __restrict__ qkv_w,
    const float* __restrict__ gate_w, const float* __restrict__ proj_w,
    bf16* __restrict__ xn, bf16* __restrict__ xbf,
    bf16* __restrict__ wqkv, bf16* __restrict__ wgate, bf16* __restrict__ wproj,
    float* __restrict__ gate_accum) {
  const int blk = blockIdx.x;
  if (blk < T_SEQ) {
    const int row = blk;
    if (row < 8) gate_accum[row * 256 + threadIdx.x] = 0.f;
    const float* xr = x + (size_t)row * DM;
    float vals[4];
    float s = 0.f, s2 = 0.f;
#pragma unroll
    for (int i = 0; i < 4; i++) {
      float v = xr[threadIdx.x + i * 256];
      vals[i] = v;
      s += v;
      s2 += v * v;
    }
#pragma unroll
    for (int m = 1; m < 64; m <<= 1) {
      s += __shfl_xor(s, m, 64);
      s2 += __shfl_xor(s2, m, 64);
    }
    __shared__ float red[8];
    const int wid = threadIdx.x >> 6;
    if ((threadIdx.x & 63) == 0) {
      red[wid] = s;
      red[4 + wid] = s2;
    }
    __syncthreads();
    s = red[0] + red[1] + red[2] + red[3];
    s2 = red[4] + red[5] + red[6] + red[7];
    const float mean = s * (1.f / DM);
    const float var = s2 * (1.f / DM) - mean * mean;
    const float rstd = rsqrtf(var + 1e-5f);
#pragma unroll
    for (int i = 0; i < 4; i++) {
      int idx = threadIdx.x + i * 256;
      float v = (vals[i] - mean) * rstd * g[idx] + b[idx];
      xn[(size_t)row * DM + idx] = __float2bfloat16(v);
      xbf[(size_t)row * DM + idx] = __float2bfloat16(vals[i]);
    }
  } else {
    constexpr int NQ = 3 * DM * DM / 4, NS = DM * DM / 4;
    int i = (blk - T_SEQ) * 256 + threadIdx.x;
    const float* src;
    bf16* dst;
    int j;
    if (i < NQ) { src = qkv_w; dst = wqkv; j = i; }
    else if (i < NQ + NS) { src = gate_w; dst = wgate; j = i - NQ; }
    else { src = proj_w; dst = wproj; j = i - NQ - NS; }
    float4 v = ((const float4*)src)[j];
    short4v sv;
    sv.x = f2b_bits(v.x); sv.y = f2b_bits(v.y); sv.z = f2b_bits(v.z); sv.w = f2b_bits(v.w);
    *(short4v*)&dst[j * 4] = sv;
  }
}

// ---------------------------------------------------------------------------
// Fused gate+qkv GEMM. R15 (best measured, 159.4us): 128x128 tile, BK=64,
// grid (32,16) = 512 blocks (2/CU), wave tile 64x64, acc[4][4] (2:1
// MFMA:ds_read, zero redundant LDS reads). XOR swizzle on [128][64]-short
// rows: LDS slot s of row r holds global chunk s^(r&7); stage source chunk
// = (tid&7)^((tid>>3)&7); read slot = (sec*4+quad)^(lm&7).
// Session evidence: pipelining (2-phase dbuf, 3-deep counted-vmcnt) and
// further conflict reduction are all NEUTRAL at this shape — the kernel is
// latency-bound at its shape (M=2048,K=1024), already above the m102 curve.
// ---------------------------------------------------------------------------
__global__ __launch_bounds__(256) void gemm_gateqkv(
    const bf16* __restrict__ xbf, const bf16* __restrict__ xn,
    const bf16* __restrict__ wg, const bf16* __restrict__ wq,
    const float* __restrict__ gate_b, const float* __restrict__ qkv_b,
    short* __restrict__ Gb, float* __restrict__ gate_accum,
    short* __restrict__ Qb, short* __restrict__ Kb, short* __restrict__ Vb,
    short* __restrict__ VbT) {
  constexpr int K = 1024;
  __shared__ __align__(16) short As[128 * 64];   // 16 KB
  __shared__ __align__(16) short Bs[128 * 64];   // 16 KB

  const int tid = threadIdx.x;
  const int wid = tid >> 6, lane = tid & 63;
  const int wm = wid >> 1, wn = wid & 1;   // wave tile 64(m) x 64(n)
  const int lm = lane & 15, quad = lane >> 4;

  const int nt = blockIdx.x;
  const bool isGate = nt < 8;
  const int m0 = blockIdx.y * 128;
  const int n0 = (isGate ? nt : nt - 8) * 128;
  const short* Ag = (const short*)(isGate ? xbf : xn);
  const short* Wg = (const short*)(isGate ? wg : wq);

  f32x4 zero = {0.f, 0.f, 0.f, 0.f};
  f32x4 acc[4][4];
#pragma unroll
  for (int i = 0; i < 4; i++)
#pragma unroll
    for (int j = 0; j < 4; j++) acc[i][j] = zero;

  // staging: per issue, 256 lanes x 16 B = 4 KB = 32 rows x 128 B.
  const int grow = tid >> 3;
  const int swq = ((tid & 7) ^ ((tid >> 3) & 7)) * 8;

  for (int kb = 0; kb < K; kb += 64) {
    __syncthreads();
#pragma unroll
    for (int it = 0; it < 4; it++) {
      const int row = it * 32 + grow;
      gload16(&Ag[(size_t)(m0 + row) * K + kb + swq], &As[it * 2048 + wid * 512]);
      gload16(&Wg[(size_t)(n0 + row) * K + kb + swq], &Bs[it * 2048 + wid * 512]);
    }
    __syncthreads();
#pragma unroll
    for (int sec = 0; sec < 2; sec++) {
      const int slot8 = (((sec * 4 + quad) ^ (lm & 7)) * 8);
      short8 afr[4], bfr[4];
#pragma unroll
      for (int i = 0; i < 4; i++)
        afr[i] = *(const short8*)&As[(wm * 64 + i * 16 + lm) * 64 + slot8];
#pragma unroll
      for (int j = 0; j < 4; j++)
        bfr[j] = *(const short8*)&Bs[(wn * 64 + j * 16 + lm) * 64 + slot8];
#pragma unroll
      for (int i = 0; i < 4; i++)
#pragma unroll
        for (int j = 0; j < 4; j++)
          acc[i][j] = __builtin_amdgcn_mfma_f32_16x16x32_bf16(afr[i], bfr[j], acc[i][j], 0, 0, 0);
    }
  }

  // epilogue: C/D layout col = lane&15, row = quad*4 + r
  if (isGate) {
    float* red = (float*)As;   // 128 rows x 32 slots = 16 KB (fits As exactly)
    __syncthreads();           // all waves' MFMA LDS reads done -> reuse As
#pragma unroll
    for (int i = 0; i < 4; i++) {
#pragma unroll
      for (int r = 0; r < 4; r++) {
        const int rowl = wm * 64 + i * 16 + quad * 4 + r;
        const int row = m0 + rowl;
        float rp = 0.f;
#pragma unroll
        for (int j = 0; j < 4; j++) {
          const int col = n0 + wn * 64 + j * 16 + lm;
          float v = acc[i][j][r] + gate_b[col];
          float sig = 1.f / (1.f + __expf(-v));
          Gb[(size_t)row * DM + col] = f2b_bits(sig);
          rp += sig;
        }
        red[rowl * 32 + wn * 16 + lm] = rp;
      }
    }
    __syncthreads();
    if (tid < 128) {
      float s = 0.f;
#pragma unroll
      for (int t2 = 0; t2 < 32; t2++) s += red[tid * 32 + t2];
      atomicAdd(&gate_accum[m0 + tid], s);
    }
  } else {
#pragma unroll
    for (int i = 0; i < 4; i++) {
      const int rbase = m0 + wm * 64 + i * 16 + quad * 4;
#pragma unroll
      for (int j = 0; j < 4; j++) {
        const int col = n0 + wn * 64 + j * 16 + lm;
        const float bval = qkv_b[col];
#pragma unroll
        for (int r = 0; r < 4; r++) {
          const int row = rbase + r;
          const short bv = f2b_bits(acc[i][j][r] + bval);
          if (col < DM) {
            const int d = col;
            Qb[((size_t)(d >> 6) * T_SEQ + row) * DH + (d & 63)] = bv;
          } else if (col < 2 * DM) {
            const int d = col - DM;
            Kb[((size_t)(d >> 6) * T_SEQ + row) * DH + (d & 63)] = bv;
          } else {
            const int d = col - 2 * DM;
            Vb[((size_t)(d >> 6) * T_SEQ + row) * DH + (d & 63)] = bv;
            VbT[((size_t)(d >> 6) * DH + (d & 63)) * T_SEQ + row] = bv;
          }
        }
      }
    }
  }
}

// ---------------------------------------------------------------------------
// Pass A: per (h,c) RAW chunk sums, stored TRANSPOSED: SkvT[m][d]. Sk_c = col
// sums of gated K. Gating during staging.
// ---------------------------------------------------------------------------
__global__ __launch_bounds__(256, 2) void chunk_sum_mm(const short* __restrict__ Kb,
                                                       const short* __restrict__ Gb,
                                                       const float* __restrict__ ga,
                                                       const short* __restrict__ Vb,
                                                       float* __restrict__ SkvT,
                                                       float* __restrict__ Sk) {
  constexpr int STR = 68;
  __shared__ __align__(16) float Ks2[64 * STR];
  __shared__ __align__(16) float Vs2[64 * STR];
  const int b = blockIdx.x;
  const int h = b >> 5, c = b & 31;
  const int tid = threadIdx.x;
  const int ty = tid >> 4, tx = tid & 15;
  const int d0 = ty * 4, m0 = tx * 4;
  const int t0 = c * CHUNK;
  const size_t cb = ((size_t)h * T_SEQ + t0) * DH;
#pragma unroll
  for (int p = 0; p < 4; p++) {
    int f = p * 256 + tid, row = f >> 4, seg = (f & 15) * 4;
    const int t = t0 + row;
    short4v kr = *(const short4v*)&Kb[cb + row * 64 + seg];
    short4v gr = *(const short4v*)&Gb[(size_t)t * DM + h * 64 + seg];
    short4v vr = *(const short4v*)&Vb[cb + row * 64 + seg];
    const float inv = 1.f / (ga[t] * (1.f / DM) + 1e-5f);
    f32x4 kgv, vv;
#pragma unroll
    for (int e = 0; e < 4; e++) {
      kgv[e] = gelu1(b2f(kr[e]), b2f(gr[e]), inv);
      vv[e] = b2f(vr[e]);
    }
    *(f32x4*)&Ks2[row * STR + seg] = kgv;
    *(f32x4*)&Vs2[row * STR + seg] = vv;
  }
  __syncthreads();
  float acc[4][4] = {};
#pragma unroll 4
  for (int s = 0; s < 64; s++) {
    f32x4 kf = *(const f32x4*)&Ks2[s * STR + d0];
    f32x4 vf = *(const f32x4*)&Vs2[s * STR + m0];
#pragma unroll
    for (int i = 0; i < 4; i++)
#pragma unroll
      for (int j = 0; j < 4; j++) acc[i][j] += kf[i] * vf[j];
  }
  float* outp = SkvT + (size_t)b * 4096;
  // transposed store: SkvT[m][d] = acc[d][m]
#pragma unroll
  for (int i = 0; i < 4; i++)
#pragma unroll
    for (int j = 0; j < 4; j++)
      outp[(m0 + j) * 64 + (d0 + i)] = acc[i][j];
  if (tid < 64) {
    float ss = 0.f;
#pragma unroll 4
    for (int s = 0; s < 64; s++) ss += Ks2[s * STR + tid];
    Sk[b * 64 + tid] = ss;
  }
}

// ---------------------------------------------------------------------------
// Pass B: exclusive prefix over chunks (elementwise, layout-agnostic).
// ---------------------------------------------------------------------------
__global__ __launch_bounds__(256) void scan_excl(float* __restrict__ Skv,
                                                 float* __restrict__ Sk) {
  const int bid = blockIdx.x, tid = threadIdx.x;
  if (bid < 256) {
    const int id = bid * 256 + tid;
    const int h = id >> 12, e = id & 4095;
    float* base = Skv + (size_t)h * NCHUNK * 4096 + e;
    float v[NCHUNK];
#pragma unroll
    for (int c = 0; c < NCHUNK; c++) v[c] = base[(size_t)c * 4096];
    float run = 0.f;
#pragma unroll
    for (int c = 0; c < NCHUNK; c++) {
      float t = v[c];
      base[(size_t)c * 4096] = run;
      run += t;
    }
  } else {
    const int id = (bid - 256) * 256 + tid;
    const int h = id >> 6, e = id & 63;
    float* base = Sk + (size_t)h * NCHUNK * 64 + e;
    float v[NCHUNK];
#pragma unroll
    for (int c = 0; c < NCHUNK; c++) v[c] = base[c * 64];
    float run = 0.f;
#pragma unroll
    for (int c = 0; c < NCHUNK; c++) {
      float t = v[c];
      base[c * 64] = run;
      run += t;
    }
  }
}

// ---------------------------------------------------------------------------
// Pass C (MFMA): per (h,c), 4 waves.
//   S = Qg.Kg^T; O^T = P^T.Qg^T + V^T.S^T; den from masked-S rowsum + q.skp.
// R13: invden dot product parallelized across all 256 threads.
// ---------------------------------------------------------------------------
__global__ __launch_bounds__(256, 2) void attn_mfma(const short* __restrict__ Qb,
                                                    const short* __restrict__ Kb,
                                                    const short* __restrict__ Gb,
                                                    const float* __restrict__ ga,
                                                    const short* __restrict__ VbT,
                                                    const float* __restrict__ SkvT,
                                                    const float* __restrict__ Sk,
                                                    bf16* __restrict__ O) {
  constexpr int STR = 72;
  __shared__ __align__(16) short Qs[64 * STR];
  __shared__ __align__(16) short Ks[64 * STR];
  __shared__ __align__(16) short Vt[64 * STR];
  __shared__ __align__(16) short Pt[64 * STR];
  __shared__ __align__(16) short SL[64 * STR];
  __shared__ float denp[64], invden[64], skp[64];
  const int b = blockIdx.x;
  const int h = b >> 5, c = b & 31;
  const int tid = threadIdx.x;
  const int wid = tid >> 6, lane = tid & 63;
  const int lm = lane & 15, quad = lane >> 4;
  const int t0 = c * CHUNK;
  const size_t cb = ((size_t)h * T_SEQ + t0) * DH;
  const float* Pg = SkvT + (size_t)b * 4096;

#pragma unroll
  for (int p = 0; p < 4; p++) {
    const int f = p * 256 + tid, row = f >> 4, seg = (f & 15) * 4;
    const int t = t0 + row;
    short4v qr = *(const short4v*)&Qb[cb + row * 64 + seg];
    short4v kr = *(const short4v*)&Kb[cb + row * 64 + seg];
    short4v gr = *(const short4v*)&Gb[(size_t)t * DM + h * 64 + seg];
    short4v vtr = *(const short4v*)&VbT[((size_t)h * DH + row) * T_SEQ + t0 + seg];
    f32x4 pr = *(const f32x4*)&Pg[row * 64 + seg];
    const float inv = 1.f / (ga[t] * (1.f / DM) + 1e-5f);
    short4v qs, ks, ps;
#pragma unroll
    for (int e = 0; e < 4; e++) {
      qs[e] = f2b_bits(gelu1(b2f(qr[e]), b2f(gr[e]), inv));
      ks[e] = f2b_bits(gelu1(b2f(kr[e]), b2f(gr[e]), inv));
      ps[e] = f2b_bits(pr[e]);
    }
    *(short4v*)&Qs[row * STR + seg] = qs;
    *(short4v*)&Ks[row * STR + seg] = ks;
    *(short4v*)&Vt[row * STR + seg] = vtr;
    *(short4v*)&Pt[row * STR + seg] = ps;
  }
  if (tid < 64) skp[tid] = Sk[b * 64 + tid];
  __syncthreads();  // B1

  f32x4 zero = {0.f, 0.f, 0.f, 0.f};
  // ---- S = Qg.Kg^T ----
  short8 aq[2];
#pragma unroll
  for (int ks = 0; ks < 2; ks++)
    aq[ks] = *(const short8*)&Qs[(wid * 16 + lm) * STR + ks * 32 + quad * 8];
  f32x4 accs[4];
#pragma unroll
  for (int j = 0; j < 4; j++) accs[j] = zero;
#pragma unroll
  for (int j = 0; j < 4; j++)
#pragma unroll
    for (int ks = 0; ks < 2; ks++) {
      short8 bk = *(const short8*)&Ks[(j * 16 + lm) * STR + ks * 32 + quad * 8];
      accs[j] = __builtin_amdgcn_mfma_f32_16x16x32_bf16(aq[ks], bk, accs[j], 0, 0, 0);
    }
  float rowpart[4] = {0.f, 0.f, 0.f, 0.f};
#pragma unroll
  for (int j = 0; j < 4; j++) {
    const int s = j * 16 + lm;
#pragma unroll
    for (int r = 0; r < 4; r++) {
      const int t = wid * 16 + quad * 4 + r;
      float v = (s <= t) ? accs[j][r] : 0.f;
      accs[j][r] = v;
      rowpart[r] += v;
    }
  }
#pragma unroll
  for (int msk = 1; msk < 16; msk <<= 1)
#pragma unroll
    for (int r = 0; r < 4; r++) rowpart[r] += __shfl_xor(rowpart[r], msk, 64);
  if (lm == 0)
#pragma unroll
    for (int r = 0; r < 4; r++) denp[wid * 16 + quad * 4 + r] = rowpart[r];
#pragma unroll
  for (int j = 0; j < 4; j++)
#pragma unroll
    for (int r = 0; r < 4; r++)
      SL[(wid * 16 + quad * 4 + r) * STR + j * 16 + lm] = f2b_bits(accs[j][r]);

  // ---- O1^T = P^T.Qg^T ----
  f32x4 acco[4];
#pragma unroll
  for (int j = 0; j < 4; j++) acco[j] = zero;
  short8 ap[2];
#pragma unroll
  for (int ks = 0; ks < 2; ks++)
    ap[ks] = *(const short8*)&Pt[(wid * 16 + lm) * STR + ks * 32 + quad * 8];
#pragma unroll
  for (int j = 0; j < 4; j++)
#pragma unroll
    for (int ks = 0; ks < 2; ks++) {
      short8 bq = *(const short8*)&Qs[(j * 16 + lm) * STR + ks * 32 + quad * 8];
      acco[j] = __builtin_amdgcn_mfma_f32_16x16x32_bf16(ap[ks], bq, acco[j], 0, 0, 0);
    }
  __syncthreads();  // B2: SL + denp complete

  {
    // all 256 threads: row = tid>>2, part = tid&3 covers 16 d each
    const int row = tid >> 2, part = tid & 3;
    float s = 0.f;
#pragma unroll
    for (int dd = 0; dd < 16; dd++) {
      const int d = part * 16 + dd;
      s += b2f(Qs[row * STR + d]) * skp[d];
    }
    s += __shfl_xor(s, 1, 64);
    s += __shfl_xor(s, 2, 64);
    if (part == 0) invden[row] = 1.f / (1e-5f + denp[row] + s);
  }

  // ---- O2^T += V^T.S^T ----
  short8 av[2];
#pragma unroll
  for (int ks = 0; ks < 2; ks++)
    av[ks] = *(const short8*)&Vt[(wid * 16 + lm) * STR + ks * 32 + quad * 8];
#pragma unroll
  for (int j = 0; j < 4; j++)
#pragma unroll
    for (int ks = 0; ks < 2; ks++) {
      short8 bs = *(const short8*)&SL[(j * 16 + lm) * STR + ks * 32 + quad * 8];
      acco[j] = __builtin_amdgcn_mfma_f32_16x16x32_bf16(av[ks], bs, acco[j], 0, 0, 0);
    }
  __syncthreads();  // B3: invden ready

#pragma unroll
  for (int j = 0; j < 4; j++) {
    const int t = j * 16 + lm;
    const float idv = invden[t];
    short4v ov;
#pragma unroll
    for (int r = 0; r < 4; r++) ov[r] = f2b_bits(acco[j][r] * idv);
    *(short4v*)&((short*)O)[(size_t)(t0 + t) * DM + h * 64 + wid * 16 + quad * 4] = ov;
  }
}

// ---------------------------------------------------------------------------
// Proj GEMM: tile 64x64, BK=64, grid (16 n-fast, 32 m) = 512 blocks (2/CU).
// T2 XOR-swizzle on the [64][32]-short layout.
// ---------------------------------------------------------------------------
__global__ __launch_bounds__(256) void gemm_proj(const bf16* __restrict__ A,
                                                 const bf16* __restrict__ W,
                                                 const float* __restrict__ bias,
                                                 float* __restrict__ Cout) {
  constexpr int K = 1024;
  __shared__ __align__(16) short As[2 * 64 * 32];
  __shared__ __align__(16) short Bs[2 * 64 * 32];

  const int tid = threadIdx.x;
  const int wid = tid >> 6, lane = tid & 63;
  const int wm = wid >> 1, wn = wid & 1;   // wave tile 32x32
  const int lm = lane & 15, quad = lane >> 4;

  const int n0 = blockIdx.x * 64;
  const int m0 = blockIdx.y * 64;
  const short* Ag = (const short*)A;
  const short* Wg = (const short*)W;

  const int arow = tid >> 2;
  const int swq = ((tid & 3) ^ ((tid >> 3) & 3)) * 8;
  const int rq8 = (quad ^ ((lm >> 1) & 3)) * 8;

  f32x4 zero = {0.f, 0.f, 0.f, 0.f};
  f32x4 acc[2][2];
#pragma unroll
  for (int i = 0; i < 2; i++)
#pragma unroll
    for (int j = 0; j < 2; j++) acc[i][j] = zero;

  for (int kb = 0; kb < K; kb += 64) {
    __syncthreads();
#pragma unroll
    for (int sec = 0; sec < 2; sec++) {
      gload16(&Ag[(size_t)(m0 + arow) * K + kb + sec * 32 + swq],
              &As[sec * 2048 + wid * 512]);
      gload16(&Wg[(size_t)(n0 + arow) * K + kb + sec * 32 + swq],
              &Bs[sec * 2048 + wid * 512]);
    }
    __syncthreads();
#pragma unroll
    for (int sec = 0; sec < 2; sec++) {
      short8 afr[2], bfr[2];
#pragma unroll
      for (int i = 0; i < 2; i++)
        afr[i] = *(const short8*)&As[sec * 2048 + (wm * 32 + i * 16 + lm) * 32 + rq8];
#pragma unroll
      for (int j = 0; j < 2; j++)
        bfr[j] = *(const short8*)&Bs[sec * 2048 + (wn * 32 + j * 16 + lm) * 32 + rq8];
#pragma unroll
      for (int i = 0; i < 2; i++)
#pragma unroll
        for (int j = 0; j < 2; j++)
          acc[i][j] = __builtin_amdgcn_mfma_f32_16x16x32_bf16(afr[i], bfr[j], acc[i][j], 0, 0, 0);
    }
  }
#pragma unroll
  for (int i = 0; i < 2; i++) {
    const int rbase = m0 + wm * 32 + i * 16 + quad * 4;
#pragma unroll
    for (int j = 0; j < 2; j++) {
      const int col = n0 + wn * 32 + j * 16 + lm;
      const float bval = bias[col];
#pragma unroll
      for (int r = 0; r < 4; r++)
        Cout[(size_t)(rbase + r) * DM + col] = acc[i][j][r] + bval;
    }
  }
}

// ---------------------------------------------------------------------------
extern "C" void kernel_launch(void* const* d_in, const int* in_sizes, int n_in,
                              void* d_out, int out_size, void* d_ws, size_t ws_size,
                              hipStream_t stream) {
  (void)in_sizes; (void)n_in; (void)out_size; (void)ws_size;
  const float* x      = (const float*)d_in[0];
  const float* ln_g   = (const float*)d_in[1];
  const float* ln_b   = (const float*)d_in[2];
  const float* qkv_w  = (const float*)d_in[3];
  const float* qkv_b  = (const float*)d_in[4];
  const float* gate_w = (const float*)d_in[5];
  const float* gate_b = (const float*)d_in[6];
  const float* proj_w = (const float*)d_in[7];
  const float* proj_b = (const float*)d_in[8];
  float* out = (float*)d_out;

  char* ws = (char*)d_ws;
  size_t off = 0;
  auto alloc = [&](size_t bytes) {
    void* p = ws + off;
    off += (bytes + 255) & ~(size_t)255;
    return p;
  };
  bf16*  xn       = (bf16*)alloc((size_t)T_SEQ * DM * 2);
  bf16*  xbf      = (bf16*)alloc((size_t)T_SEQ * DM * 2);
  bf16*  wqkv     = (bf16*)alloc((size_t)3 * DM * DM * 2);
  bf16*  wgate    = (bf16*)alloc((size_t)DM * DM * 2);
  bf16*  wproj    = (bf16*)alloc((size_t)DM * DM * 2);
  short* Gb       = (short*)alloc((size_t)T_SEQ * DM * 2);
  float* gate_accum = (float*)alloc((size_t)T_SEQ * 4);
  short* Qb       = (short*)alloc((size_t)T_SEQ * DM * 2);
  short* Kb       = (short*)alloc((size_t)T_SEQ * DM * 2);
  short* Vb       = (short*)alloc((size_t)T_SEQ * DM * 2);
  short* VbT      = (short*)alloc((size_t)T_SEQ * DM * 2);
  bf16*  Obuf     = (bf16*)alloc((size_t)T_SEQ * DM * 2);
  float* SkvT     = (float*)alloc((size_t)NH * NCHUNK * 4096 * 4);
  float* Sk       = (float*)alloc((size_t)NH * NCHUNK * 64 * 4);

  prep_kernel<<<T_SEQ + PREP_WBLOCKS, 256, 0, stream>>>(
      x, ln_g, ln_b, qkv_w, gate_w, proj_w, xn, xbf, wqkv, wgate, wproj, gate_accum);
  gemm_gateqkv<<<dim3(32, 16), 256, 0, stream>>>(xbf, xn, wgate, wqkv, gate_b, qkv_b,
                                                 Gb, gate_accum, Qb, Kb, Vb, VbT);
  chunk_sum_mm<<<NH * NCHUNK, 256, 0, stream>>>(Kb, Gb, gate_accum, Vb, SkvT, Sk);
  scan_excl<<<260, 256, 0, stream>>>(SkvT, Sk);
  attn_mfma<<<NH * NCHUNK, 256, 0, stream>>>(Qb, Kb, Gb, gate_accum, VbT, SkvT, Sk, Obuf);
  gemm_proj<<<dim3(16, 32), 256, 0, stream>>>(Obuf, wproj, proj_b, out);
}

// Round 12
// 153.294 us; speedup vs baseline: 6.4745x; 1.0407x over previous
//
#include <hip/hip_runtime.h>
#include <hip/hip_bf16.h>
#include <math.h>

#define T_SEQ 2048
#define DM 1024
#define NH 16
#define DH 64
#define CHUNK 64
#define NCHUNK (T_SEQ / CHUNK)   // 32

typedef __hip_bfloat16 bf16;
typedef __attribute__((ext_vector_type(8))) short short8;
typedef __attribute__((ext_vector_type(4))) short short4v;
typedef __attribute__((ext_vector_type(4))) float f32x4;

static __device__ __forceinline__ short f2b_bits(float f) {
  bf16 t = __float2bfloat16(f);
  short s;
  __builtin_memcpy(&s, &t, 2);
  return s;
}
static __device__ __forceinline__ float b2f(short s) {
  unsigned int u = ((unsigned int)(unsigned short)s) << 16;
  float f;
  __builtin_memcpy(&f, &u, 4);
  return f;
}
// gated ELU+1: elu(x)+1 = x>0 ? x+1 : exp(x)
static __device__ __forceinline__ float gelu1(float raw, float gate, float inv) {
  float x = raw * gate * inv;
  return x > 0.f ? x + 1.f : __expf(x);
}
static __device__ __forceinline__ void gload16(const void* g, void* l) {
  __builtin_amdgcn_global_load_lds((const __attribute__((address_space(1))) void*)g,
                                   (__attribute__((address_space(3))) void*)l, 16, 0, 0);
}

// ---------------------------------------------------------------------------
// prep: blocks 0..2047 = LayerNorm rows (blocks 0..7 also zero gate_accum);
//       blocks 2048..  = fp32->bf16 weight conversion (qkv|gate|proj).
// ---------------------------------------------------------------------------
#define PREP_WBLOCKS (5 * DM * DM / 4 / 256)   // 5120
__global__ __launch_bounds__(256) void prep_kernel(
    const float* __restrict__ x, const float* __restrict__ g,
    const float* __restrict__ b, const float* __restrict__ qkv_w,
    const float* __restrict__ gate_w, const float* __restrict__ proj_w,
    bf16* __restrict__ xn, bf16* __restrict__ xbf,
    bf16* __restrict__ wqkv, bf16* __restrict__ wgate, bf16* __restrict__ wproj,
    float* __restrict__ gate_accum) {
  const int blk = blockIdx.x;
  if (blk < T_SEQ) {
    const int row = blk;
    if (row < 8) gate_accum[row * 256 + threadIdx.x] = 0.f;
    const float* xr = x + (size_t)row * DM;
    float vals[4];
    float s = 0.f, s2 = 0.f;
#pragma unroll
    for (int i = 0; i < 4; i++) {
      float v = xr[threadIdx.x + i * 256];
      vals[i] = v;
      s += v;
      s2 += v * v;
    }
#pragma unroll
    for (int m = 1; m < 64; m <<= 1) {
      s += __shfl_xor(s, m, 64);
      s2 += __shfl_xor(s2, m, 64);
    }
    __shared__ float red[8];
    const int wid = threadIdx.x >> 6;
    if ((threadIdx.x & 63) == 0) {
      red[wid] = s;
      red[4 + wid] = s2;
    }
    __syncthreads();
    s = red[0] + red[1] + red[2] + red[3];
    s2 = red[4] + red[5] + red[6] + red[7];
    const float mean = s * (1.f / DM);
    const float var = s2 * (1.f / DM) - mean * mean;
    const float rstd = rsqrtf(var + 1e-5f);
#pragma unroll
    for (int i = 0; i < 4; i++) {
      int idx = threadIdx.x + i * 256;
      float v = (vals[i] - mean) * rstd * g[idx] + b[idx];
      xn[(size_t)row * DM + idx] = __float2bfloat16(v);
      xbf[(size_t)row * DM + idx] = __float2bfloat16(vals[i]);
    }
  } else {
    constexpr int NQ = 3 * DM * DM / 4, NS = DM * DM / 4;
    int i = (blk - T_SEQ) * 256 + threadIdx.x;
    const float* src;
    bf16* dst;
    int j;
    if (i < NQ) { src = qkv_w; dst = wqkv; j = i; }
    else if (i < NQ + NS) { src = gate_w; dst = wgate; j = i - NQ; }
    else { src = proj_w; dst = wproj; j = i - NQ - NS; }
    float4 v = ((const float4*)src)[j];
    short4v sv;
    sv.x = f2b_bits(v.x); sv.y = f2b_bits(v.y); sv.z = f2b_bits(v.z); sv.w = f2b_bits(v.w);
    *(short4v*)&dst[j * 4] = sv;
  }
}

// ---------------------------------------------------------------------------
// Fused gate+qkv GEMM. R23: R15's 128x128 tile with BK=128 (8 K-steps
// instead of 16). The per-K-step barrier drain (~700-900 cy, fixed per step
// regardless of payload -- R19 PMC arithmetic) is the measured dominant
// cost; halving the step count halves the number of drains while total
// issue work is constant. m132's BK=128 regression was an occupancy step
// 3->2 blocks/CU; inapplicable here: grid already caps at 2/CU and
// 64 KB LDS x2 = 128 KB < 160 KB keeps 2/CU.
// Swizzle for 256B rows (16 chunks of 16B): LDS slot s of row r holds
// global chunk s^(r&15); stage source chunk (tid&15)^((tid>>4)&15); read
// slot (sec*4+quad)^lm. 64 lanes spread 16 slots x4 -> 8 lanes per 4-bank
// group x 8 groups = exactly the 8-cy LDS BW floor (no effective conflict).
// ---------------------------------------------------------------------------
__global__ __launch_bounds__(256) void gemm_gateqkv(
    const bf16* __restrict__ xbf, const bf16* __restrict__ xn,
    const bf16* __restrict__ wg, const bf16* __restrict__ wq,
    const float* __restrict__ gate_b, const float* __restrict__ qkv_b,
    short* __restrict__ Gb, float* __restrict__ gate_accum,
    short* __restrict__ Qb, short* __restrict__ Kb, short* __restrict__ Vb,
    short* __restrict__ VbT) {
  constexpr int K = 1024;
  __shared__ __align__(16) short As[128 * 128];   // 32 KB
  __shared__ __align__(16) short Bs[128 * 128];   // 32 KB

  const int tid = threadIdx.x;
  const int wid = tid >> 6, lane = tid & 63;
  const int wm = wid >> 1, wn = wid & 1;   // wave tile 64(m) x 64(n)
  const int lm = lane & 15, quad = lane >> 4;

  const int nt = blockIdx.x;
  const bool isGate = nt < 8;
  const int m0 = blockIdx.y * 128;
  const int n0 = (isGate ? nt : nt - 8) * 128;
  const short* Ag = (const short*)(isGate ? xbf : xn);
  const short* Wg = (const short*)(isGate ? wg : wq);

  f32x4 zero = {0.f, 0.f, 0.f, 0.f};
  f32x4 acc[4][4];
#pragma unroll
  for (int i = 0; i < 4; i++)
#pragma unroll
    for (int j = 0; j < 4; j++) acc[i][j] = zero;

  // staging: per issue, 256 lanes x 16 B = 4 KB = 16 rows x 256 B.
  const int grow = tid >> 4;
  const int swq = ((tid & 15) ^ ((tid >> 4) & 15)) * 8;

  for (int kb = 0; kb < K; kb += 128) {
    __syncthreads();
#pragma unroll
    for (int it = 0; it < 8; it++) {
      const int row = it * 16 + grow;
      gload16(&Ag[(size_t)(m0 + row) * K + kb + swq], &As[it * 2048 + wid * 512]);
      gload16(&Wg[(size_t)(n0 + row) * K + kb + swq], &Bs[it * 2048 + wid * 512]);
    }
    __syncthreads();
#pragma unroll
    for (int sec = 0; sec < 4; sec++) {
      const int slot8 = (((sec * 4 + quad) ^ lm) * 8);
      short8 afr[4], bfr[4];
#pragma unroll
      for (int i = 0; i < 4; i++)
        afr[i] = *(const short8*)&As[(wm * 64 + i * 16 + lm) * 128 + slot8];
#pragma unroll
      for (int j = 0; j < 4; j++)
        bfr[j] = *(const short8*)&Bs[(wn * 64 + j * 16 + lm) * 128 + slot8];
#pragma unroll
      for (int i = 0; i < 4; i++)
#pragma unroll
        for (int j = 0; j < 4; j++)
          acc[i][j] = __builtin_amdgcn_mfma_f32_16x16x32_bf16(afr[i], bfr[j], acc[i][j], 0, 0, 0);
    }
  }

  // epilogue: C/D layout col = lane&15, row = quad*4 + r
  if (isGate) {
    float* red = (float*)As;   // 128 rows x 32 slots = 16 KB (fits in 32 KB As)
    __syncthreads();           // all waves' MFMA LDS reads done -> reuse As
#pragma unroll
    for (int i = 0; i < 4; i++) {
#pragma unroll
      for (int r = 0; r < 4; r++) {
        const int rowl = wm * 64 + i * 16 + quad * 4 + r;
        const int row = m0 + rowl;
        float rp = 0.f;
#pragma unroll
        for (int j = 0; j < 4; j++) {
          const int col = n0 + wn * 64 + j * 16 + lm;
          float v = acc[i][j][r] + gate_b[col];
          float sig = 1.f / (1.f + __expf(-v));
          Gb[(size_t)row * DM + col] = f2b_bits(sig);
          rp += sig;
        }
        red[rowl * 32 + wn * 16 + lm] = rp;
      }
    }
    __syncthreads();
    if (tid < 128) {
      float s = 0.f;
#pragma unroll
      for (int t2 = 0; t2 < 32; t2++) s += red[tid * 32 + t2];
      atomicAdd(&gate_accum[m0 + tid], s);
    }
  } else {
#pragma unroll
    for (int i = 0; i < 4; i++) {
      const int rbase = m0 + wm * 64 + i * 16 + quad * 4;
#pragma unroll
      for (int j = 0; j < 4; j++) {
        const int col = n0 + wn * 64 + j * 16 + lm;
        const float bval = qkv_b[col];
#pragma unroll
        for (int r = 0; r < 4; r++) {
          const int row = rbase + r;
          const short bv = f2b_bits(acc[i][j][r] + bval);
          if (col < DM) {
            const int d = col;
            Qb[((size_t)(d >> 6) * T_SEQ + row) * DH + (d & 63)] = bv;
          } else if (col < 2 * DM) {
            const int d = col - DM;
            Kb[((size_t)(d >> 6) * T_SEQ + row) * DH + (d & 63)] = bv;
          } else {
            const int d = col - 2 * DM;
            Vb[((size_t)(d >> 6) * T_SEQ + row) * DH + (d & 63)] = bv;
            VbT[((size_t)(d >> 6) * DH + (d & 63)) * T_SEQ + row] = bv;
          }
        }
      }
    }
  }
}

// ---------------------------------------------------------------------------
// Pass A: per (h,c) RAW chunk sums, stored TRANSPOSED: SkvT[m][d]. Sk_c = col
// sums of gated K. Gating during staging.
// ---------------------------------------------------------------------------
__global__ __launch_bounds__(256, 2) void chunk_sum_mm(const short* __restrict__ Kb,
                                                       const short* __restrict__ Gb,
                                                       const float* __restrict__ ga,
                                                       const short* __restrict__ Vb,
                                                       float* __restrict__ SkvT,
                                                       float* __restrict__ Sk) {
  constexpr int STR = 68;
  __shared__ __align__(16) float Ks2[64 * STR];
  __shared__ __align__(16) float Vs2[64 * STR];
  const int b = blockIdx.x;
  const int h = b >> 5, c = b & 31;
  const int tid = threadIdx.x;
  const int ty = tid >> 4, tx = tid & 15;
  const int d0 = ty * 4, m0 = tx * 4;
  const int t0 = c * CHUNK;
  const size_t cb = ((size_t)h * T_SEQ + t0) * DH;
#pragma unroll
  for (int p = 0; p < 4; p++) {
    int f = p * 256 + tid, row = f >> 4, seg = (f & 15) * 4;
    const int t = t0 + row;
    short4v kr = *(const short4v*)&Kb[cb + row * 64 + seg];
    short4v gr = *(const short4v*)&Gb[(size_t)t * DM + h * 64 + seg];
    short4v vr = *(const short4v*)&Vb[cb + row * 64 + seg];
    const float inv = 1.f / (ga[t] * (1.f / DM) + 1e-5f);
    f32x4 kgv, vv;
#pragma unroll
    for (int e = 0; e < 4; e++) {
      kgv[e] = gelu1(b2f(kr[e]), b2f(gr[e]), inv);
      vv[e] = b2f(vr[e]);
    }
    *(f32x4*)&Ks2[row * STR + seg] = kgv;
    *(f32x4*)&Vs2[row * STR + seg] = vv;
  }
  __syncthreads();
  float acc[4][4] = {};
#pragma unroll 4
  for (int s = 0; s < 64; s++) {
    f32x4 kf = *(const f32x4*)&Ks2[s * STR + d0];
    f32x4 vf = *(const f32x4*)&Vs2[s * STR + m0];
#pragma unroll
    for (int i = 0; i < 4; i++)
#pragma unroll
      for (int j = 0; j < 4; j++) acc[i][j] += kf[i] * vf[j];
  }
  float* outp = SkvT + (size_t)b * 4096;
  // transposed store: SkvT[m][d] = acc[d][m]
#pragma unroll
  for (int i = 0; i < 4; i++)
#pragma unroll
    for (int j = 0; j < 4; j++)
      outp[(m0 + j) * 64 + (d0 + i)] = acc[i][j];
  if (tid < 64) {
    float ss = 0.f;
#pragma unroll 4
    for (int s = 0; s < 64; s++) ss += Ks2[s * STR + tid];
    Sk[b * 64 + tid] = ss;
  }
}

// ---------------------------------------------------------------------------
// Pass B: exclusive prefix over chunks (elementwise, layout-agnostic).
// ---------------------------------------------------------------------------
__global__ __launch_bounds__(256) void scan_excl(float* __restrict__ Skv,
                                                 float* __restrict__ Sk) {
  const int bid = blockIdx.x, tid = threadIdx.x;
  if (bid < 256) {
    const int id = bid * 256 + tid;
    const int h = id >> 12, e = id & 4095;
    float* base = Skv + (size_t)h * NCHUNK * 4096 + e;
    float v[NCHUNK];
#pragma unroll
    for (int c = 0; c < NCHUNK; c++) v[c] = base[(size_t)c * 4096];
    float run = 0.f;
#pragma unroll
    for (int c = 0; c < NCHUNK; c++) {
      float t = v[c];
      base[(size_t)c * 4096] = run;
      run += t;
    }
  } else {
    const int id = (bid - 256) * 256 + tid;
    const int h = id >> 6, e = id & 63;
    float* base = Sk + (size_t)h * NCHUNK * 64 + e;
    float v[NCHUNK];
#pragma unroll
    for (int c = 0; c < NCHUNK; c++) v[c] = base[c * 64];
    float run = 0.f;
#pragma unroll
    for (int c = 0; c < NCHUNK; c++) {
      float t = v[c];
      base[c * 64] = run;
      run += t;
    }
  }
}

// ---------------------------------------------------------------------------
// Pass C (MFMA): per (h,c), 4 waves.
//   S = Qg.Kg^T; O^T = P^T.Qg^T + V^T.S^T; den from masked-S rowsum + q.skp.
// R13: invden dot product parallelized across all 256 threads.
// ---------------------------------------------------------------------------
__global__ __launch_bounds__(256, 2) void attn_mfma(const short* __restrict__ Qb,
                                                    const short* __restrict__ Kb,
                                                    const short* __restrict__ Gb,
                                                    const float* __restrict__ ga,
                                                    const short* __restrict__ VbT,
                                                    const float* __restrict__ SkvT,
                                                    const float* __restrict__ Sk,
                                                    bf16* __restrict__ O) {
  constexpr int STR = 72;
  __shared__ __align__(16) short Qs[64 * STR];
  __shared__ __align__(16) short Ks[64 * STR];
  __shared__ __align__(16) short Vt[64 * STR];
  __shared__ __align__(16) short Pt[64 * STR];
  __shared__ __align__(16) short SL[64 * STR];
  __shared__ float denp[64], invden[64], skp[64];
  const int b = blockIdx.x;
  const int h = b >> 5, c = b & 31;
  const int tid = threadIdx.x;
  const int wid = tid >> 6, lane = tid & 63;
  const int lm = lane & 15, quad = lane >> 4;
  const int t0 = c * CHUNK;
  const size_t cb = ((size_t)h * T_SEQ + t0) * DH;
  const float* Pg = SkvT + (size_t)b * 4096;

#pragma unroll
  for (int p = 0; p < 4; p++) {
    const int f = p * 256 + tid, row = f >> 4, seg = (f & 15) * 4;
    const int t = t0 + row;
    short4v qr = *(const short4v*)&Qb[cb + row * 64 + seg];
    short4v kr = *(const short4v*)&Kb[cb + row * 64 + seg];
    short4v gr = *(const short4v*)&Gb[(size_t)t * DM + h * 64 + seg];
    short4v vtr = *(const short4v*)&VbT[((size_t)h * DH + row) * T_SEQ + t0 + seg];
    f32x4 pr = *(const f32x4*)&Pg[row * 64 + seg];
    const float inv = 1.f / (ga[t] * (1.f / DM) + 1e-5f);
    short4v qs, ks, ps;
#pragma unroll
    for (int e = 0; e < 4; e++) {
      qs[e] = f2b_bits(gelu1(b2f(qr[e]), b2f(gr[e]), inv));
      ks[e] = f2b_bits(gelu1(b2f(kr[e]), b2f(gr[e]), inv));
      ps[e] = f2b_bits(pr[e]);
    }
    *(short4v*)&Qs[row * STR + seg] = qs;
    *(short4v*)&Ks[row * STR + seg] = ks;
    *(short4v*)&Vt[row * STR + seg] = vtr;
    *(short4v*)&Pt[row * STR + seg] = ps;
  }
  if (tid < 64) skp[tid] = Sk[b * 64 + tid];
  __syncthreads();  // B1

  f32x4 zero = {0.f, 0.f, 0.f, 0.f};
  // ---- S = Qg.Kg^T ----
  short8 aq[2];
#pragma unroll
  for (int ks = 0; ks < 2; ks++)
    aq[ks] = *(const short8*)&Qs[(wid * 16 + lm) * STR + ks * 32 + quad * 8];
  f32x4 accs[4];
#pragma unroll
  for (int j = 0; j < 4; j++) accs[j] = zero;
#pragma unroll
  for (int j = 0; j < 4; j++)
#pragma unroll
    for (int ks = 0; ks < 2; ks++) {
      short8 bk = *(const short8*)&Ks[(j * 16 + lm) * STR + ks * 32 + quad * 8];
      accs[j] = __builtin_amdgcn_mfma_f32_16x16x32_bf16(aq[ks], bk, accs[j], 0, 0, 0);
    }
  float rowpart[4] = {0.f, 0.f, 0.f, 0.f};
#pragma unroll
  for (int j = 0; j < 4; j++) {
    const int s = j * 16 + lm;
#pragma unroll
    for (int r = 0; r < 4; r++) {
      const int t = wid * 16 + quad * 4 + r;
      float v = (s <= t) ? accs[j][r] : 0.f;
      accs[j][r] = v;
      rowpart[r] += v;
    }
  }
#pragma unroll
  for (int msk = 1; msk < 16; msk <<= 1)
#pragma unroll
    for (int r = 0; r < 4; r++) rowpart[r] += __shfl_xor(rowpart[r], msk, 64);
  if (lm == 0)
#pragma unroll
    for (int r = 0; r < 4; r++) denp[wid * 16 + quad * 4 + r] = rowpart[r];
#pragma unroll
  for (int j = 0; j < 4; j++)
#pragma unroll
    for (int r = 0; r < 4; r++)
      SL[(wid * 16 + quad * 4 + r) * STR + j * 16 + lm] = f2b_bits(accs[j][r]);

  // ---- O1^T = P^T.Qg^T ----
  f32x4 acco[4];
#pragma unroll
  for (int j = 0; j < 4; j++) acco[j] = zero;
  short8 ap[2];
#pragma unroll
  for (int ks = 0; ks < 2; ks++)
    ap[ks] = *(const short8*)&Pt[(wid * 16 + lm) * STR + ks * 32 + quad * 8];
#pragma unroll
  for (int j = 0; j < 4; j++)
#pragma unroll
    for (int ks = 0; ks < 2; ks++) {
      short8 bq = *(const short8*)&Qs[(j * 16 + lm) * STR + ks * 32 + quad * 8];
      acco[j] = __builtin_amdgcn_mfma_f32_16x16x32_bf16(ap[ks], bq, acco[j], 0, 0, 0);
    }
  __syncthreads();  // B2: SL + denp complete

  {
    // all 256 threads: row = tid>>2, part = tid&3 covers 16 d each
    const int row = tid >> 2, part = tid & 3;
    float s = 0.f;
#pragma unroll
    for (int dd = 0; dd < 16; dd++) {
      const int d = part * 16 + dd;
      s += b2f(Qs[row * STR + d]) * skp[d];
    }
    s += __shfl_xor(s, 1, 64);
    s += __shfl_xor(s, 2, 64);
    if (part == 0) invden[row] = 1.f / (1e-5f + denp[row] + s);
  }

  // ---- O2^T += V^T.S^T ----
  short8 av[2];
#pragma unroll
  for (int ks = 0; ks < 2; ks++)
    av[ks] = *(const short8*)&Vt[(wid * 16 + lm) * STR + ks * 32 + quad * 8];
#pragma unroll
  for (int j = 0; j < 4; j++)
#pragma unroll
    for (int ks = 0; ks < 2; ks++) {
      short8 bs = *(const short8*)&SL[(j * 16 + lm) * STR + ks * 32 + quad * 8];
      acco[j] = __builtin_amdgcn_mfma_f32_16x16x32_bf16(av[ks], bs, acco[j], 0, 0, 0);
    }
  __syncthreads();  // B3: invden ready

#pragma unroll
  for (int j = 0; j < 4; j++) {
    const int t = j * 16 + lm;
    const float idv = invden[t];
    short4v ov;
#pragma unroll
    for (int r = 0; r < 4; r++) ov[r] = f2b_bits(acco[j][r] * idv);
    *(short4v*)&((short*)O)[(size_t)(t0 + t) * DM + h * 64 + wid * 16 + quad * 4] = ov;
  }
}

// ---------------------------------------------------------------------------
// Proj GEMM: tile 64x64, grid (16 n-fast, 32 m) = 512 blocks (2/CU).
// R23: BK=128 (8 K-steps instead of 16) -- same drain-halving rationale as
// gemm_gateqkv. LDS 2x16KB=32KB. Swizzle for 256B rows as in gateqkv.
// ---------------------------------------------------------------------------
__global__ __launch_bounds__(256) void gemm_proj(const bf16* __restrict__ A,
                                                 const bf16* __restrict__ W,
                                                 const float* __restrict__ bias,
                                                 float* __restrict__ Cout) {
  constexpr int K = 1024;
  __shared__ __align__(16) short As[64 * 128];   // 16 KB
  __shared__ __align__(16) short Bs[64 * 128];   // 16 KB

  const int tid = threadIdx.x;
  const int wid = tid >> 6, lane = tid & 63;
  const int wm = wid >> 1, wn = wid & 1;   // wave tile 32x32
  const int lm = lane & 15, quad = lane >> 4;

  const int n0 = blockIdx.x * 64;
  const int m0 = blockIdx.y * 64;
  const short* Ag = (const short*)A;
  const short* Wg = (const short*)W;

  // staging: per issue, 256 lanes x 16 B = 4 KB = 16 rows x 256 B.
  const int grow = tid >> 4;
  const int swq = ((tid & 15) ^ ((tid >> 4) & 15)) * 8;

  f32x4 zero = {0.f, 0.f, 0.f, 0.f};
  f32x4 acc[2][2];
#pragma unroll
  for (int i = 0; i < 2; i++)
#pragma unroll
    for (int j = 0; j < 2; j++) acc[i][j] = zero;

  for (int kb = 0; kb < K; kb += 128) {
    __syncthreads();
#pragma unroll
    for (int it = 0; it < 4; it++) {
      const int row = it * 16 + grow;
      gload16(&Ag[(size_t)(m0 + row) * K + kb + swq], &As[it * 2048 + wid * 512]);
      gload16(&Wg[(size_t)(n0 + row) * K + kb + swq], &Bs[it * 2048 + wid * 512]);
    }
    __syncthreads();
#pragma unroll
    for (int sec = 0; sec < 4; sec++) {
      const int slot8 = (((sec * 4 + quad) ^ lm) * 8);
      short8 afr[2], bfr[2];
#pragma unroll
      for (int i = 0; i < 2; i++)
        afr[i] = *(const short8*)&As[(wm * 32 + i * 16 + lm) * 128 + slot8];
#pragma unroll
      for (int j = 0; j < 2; j++)
        bfr[j] = *(const short8*)&Bs[(wn * 32 + j * 16 + lm) * 128 + slot8];
#pragma unroll
      for (int i = 0; i < 2; i++)
#pragma unroll
        for (int j = 0; j < 2; j++)
          acc[i][j] = __builtin_amdgcn_mfma_f32_16x16x32_bf16(afr[i], bfr[j], acc[i][j], 0, 0, 0);
    }
  }
#pragma unroll
  for (int i = 0; i < 2; i++) {
    const int rbase = m0 + wm * 32 + i * 16 + quad * 4;
#pragma unroll
    for (int j = 0; j < 2; j++) {
      const int col = n0 + wn * 32 + j * 16 + lm;
      const float bval = bias[col];
#pragma unroll
      for (int r = 0; r < 4; r++)
        Cout[(size_t)(rbase + r) * DM + col] = acc[i][j][r] + bval;
    }
  }
}

// ---------------------------------------------------------------------------
extern "C" void kernel_launch(void* const* d_in, const int* in_sizes, int n_in,
                              void* d_out, int out_size, void* d_ws, size_t ws_size,
                              hipStream_t stream) {
  (void)in_sizes; (void)n_in; (void)out_size; (void)ws_size;
  const float* x      = (const float*)d_in[0];
  const float* ln_g   = (const float*)d_in[1];
  const float* ln_b   = (const float*)d_in[2];
  const float* qkv_w  = (const float*)d_in[3];
  const float* qkv_b  = (const float*)d_in[4];
  const float* gate_w = (const float*)d_in[5];
  const float* gate_b = (const float*)d_in[6];
  const float* proj_w = (const float*)d_in[7];
  const float* proj_b = (const float*)d_in[8];
  float* out = (float*)d_out;

  char* ws = (char*)d_ws;
  size_t off = 0;
  auto alloc = [&](size_t bytes) {
    void* p = ws + off;
    off += (bytes + 255) & ~(size_t)255;
    return p;
  };
  bf16*  xn       = (bf16*)alloc((size_t)T_SEQ * DM * 2);
  bf16*  xbf      = (bf16*)alloc((size_t)T_SEQ * DM * 2);
  bf16*  wqkv     = (bf16*)alloc((size_t)3 * DM * DM * 2);
  bf16*  wgate    = (bf16*)alloc((size_t)DM * DM * 2);
  bf16*  wproj    = (bf16*)alloc((size_t)DM * DM * 2);
  short* Gb       = (short*)alloc((size_t)T_SEQ * DM * 2);
  float* gate_accum = (float*)alloc((size_t)T_SEQ * 4);
  short* Qb       = (short*)alloc((size_t)T_SEQ * DM * 2);
  short* Kb       = (short*)alloc((size_t)T_SEQ * DM * 2);
  short* Vb       = (short*)alloc((size_t)T_SEQ * DM * 2);
  short* VbT      = (short*)alloc((size_t)T_SEQ * DM * 2);
  bf16*  Obuf     = (bf16*)alloc((size_t)T_SEQ * DM * 2);
  float* SkvT     = (float*)alloc((size_t)NH * NCHUNK * 4096 * 4);
  float* Sk       = (float*)alloc((size_t)NH * NCHUNK * 64 * 4);

  prep_kernel<<<T_SEQ + PREP_WBLOCKS, 256, 0, stream>>>(
      x, ln_g, ln_b, qkv_w, gate_w, proj_w, xn, xbf, wqkv, wgate, wproj, gate_accum);
  gemm_gateqkv<<<dim3(32, 16), 256, 0, stream>>>(xbf, xn, wgate, wqkv, gate_b, qkv_b,
                                                 Gb, gate_accum, Qb, Kb, Vb, VbT);
  chunk_sum_mm<<<NH * NCHUNK, 256, 0, stream>>>(Kb, Gb, gate_accum, Vb, SkvT, Sk);
  scan_excl<<<260, 256, 0, stream>>>(SkvT, Sk);
  attn_mfma<<<NH * NCHUNK, 256, 0, stream>>>(Qb, Kb, Gb, gate_accum, VbT, SkvT, Sk, Obuf);
  gemm_proj<<<dim3(16, 32), 256, 0, stream>>>(Obuf, wproj, proj_b, out);
}

// Round 13
// 151.688 us; speedup vs baseline: 6.5431x; 1.0106x over previous
//
#include <hip/hip_runtime.h>
#include <hip/hip_bf16.h>
#include <math.h>

#define T_SEQ 2048
#define DM 1024
#define NH 16
#define DH 64
#define CHUNK 64
#define NCHUNK (T_SEQ / CHUNK)   // 32

typedef __hip_bfloat16 bf16;
typedef __attribute__((ext_vector_type(8))) short short8;
typedef __attribute__((ext_vector_type(4))) short short4v;
typedef __attribute__((ext_vector_type(4))) float f32x4;

static __device__ __forceinline__ short f2b_bits(float f) {
  bf16 t = __float2bfloat16(f);
  short s;
  __builtin_memcpy(&s, &t, 2);
  return s;
}
static __device__ __forceinline__ float b2f(short s) {
  unsigned int u = ((unsigned int)(unsigned short)s) << 16;
  float f;
  __builtin_memcpy(&f, &u, 4);
  return f;
}
// gated ELU+1: elu(x)+1 = x>0 ? x+1 : exp(x)
static __device__ __forceinline__ float gelu1(float raw, float gate, float inv) {
  float x = raw * gate * inv;
  return x > 0.f ? x + 1.f : __expf(x);
}
static __device__ __forceinline__ void gload16(const void* g, void* l) {
  __builtin_amdgcn_global_load_lds((const __attribute__((address_space(1))) void*)g,
                                   (__attribute__((address_space(3))) void*)l, 16, 0, 0);
}

// ---------------------------------------------------------------------------
// prep: blocks 0..2047 = LayerNorm rows (blocks 0..7 also zero gate_accum);
//       blocks 2048..  = fp32->bf16 weight conversion (qkv|gate|proj).
// ---------------------------------------------------------------------------
#define PREP_WBLOCKS (5 * DM * DM / 4 / 256)   // 5120
__global__ __launch_bounds__(256) void prep_kernel(
    const float* __restrict__ x, const float* __restrict__ g,
    const float* __restrict__ b, const float* __restrict__ qkv_w,
    const float* __restrict__ gate_w, const float* __restrict__ proj_w,
    bf16* __restrict__ xn, bf16* __restrict__ xbf,
    bf16* __restrict__ wqkv, bf16* __restrict__ wgate, bf16* __restrict__ wproj,
    float* __restrict__ gate_accum) {
  const int blk = blockIdx.x;
  if (blk < T_SEQ) {
    const int row = blk;
    if (row < 8) gate_accum[row * 256 + threadIdx.x] = 0.f;
    const float* xr = x + (size_t)row * DM;
    float vals[4];
    float s = 0.f, s2 = 0.f;
#pragma unroll
    for (int i = 0; i < 4; i++) {
      float v = xr[threadIdx.x + i * 256];
      vals[i] = v;
      s += v;
      s2 += v * v;
    }
#pragma unroll
    for (int m = 1; m < 64; m <<= 1) {
      s += __shfl_xor(s, m, 64);
      s2 += __shfl_xor(s2, m, 64);
    }
    __shared__ float red[8];
    const int wid = threadIdx.x >> 6;
    if ((threadIdx.x & 63) == 0) {
      red[wid] = s;
      red[4 + wid] = s2;
    }
    __syncthreads();
    s = red[0] + red[1] + red[2] + red[3];
    s2 = red[4] + red[5] + red[6] + red[7];
    const float mean = s * (1.f / DM);
    const float var = s2 * (1.f / DM) - mean * mean;
    const float rstd = rsqrtf(var + 1e-5f);
#pragma unroll
    for (int i = 0; i < 4; i++) {
      int idx = threadIdx.x + i * 256;
      float v = (vals[i] - mean) * rstd * g[idx] + b[idx];
      xn[(size_t)row * DM + idx] = __float2bfloat16(v);
      xbf[(size_t)row * DM + idx] = __float2bfloat16(vals[i]);
    }
  } else {
    constexpr int NQ = 3 * DM * DM / 4, NS = DM * DM / 4;
    int i = (blk - T_SEQ) * 256 + threadIdx.x;
    const float* src;
    bf16* dst;
    int j;
    if (i < NQ) { src = qkv_w; dst = wqkv; j = i; }
    else if (i < NQ + NS) { src = gate_w; dst = wgate; j = i - NQ; }
    else { src = proj_w; dst = wproj; j = i - NQ - NS; }
    float4 v = ((const float4*)src)[j];
    short4v sv;
    sv.x = f2b_bits(v.x); sv.y = f2b_bits(v.y); sv.z = f2b_bits(v.z); sv.w = f2b_bits(v.w);
    *(short4v*)&dst[j * 4] = sv;
  }
}

// ---------------------------------------------------------------------------
// Fused gate+qkv GEMM. R23 (best measured, 153.3us total): 128x128 tile,
// BK=128, 8 K-steps. Per-K-step barrier drain is a fixed ~800cy cost
// (R19 PMC arithmetic); halving step count 16->8 was the confirmed win
// (R22 159.5 -> R23 153.3). LDS 2x32KB=64KB, 2 blocks/CU (grid-capped).
// Swizzle for 256B rows: slot s of row r holds chunk s^(r&15).
// ---------------------------------------------------------------------------
__global__ __launch_bounds__(256) void gemm_gateqkv(
    const bf16* __restrict__ xbf, const bf16* __restrict__ xn,
    const bf16* __restrict__ wg, const bf16* __restrict__ wq,
    const float* __restrict__ gate_b, const float* __restrict__ qkv_b,
    short* __restrict__ Gb, float* __restrict__ gate_accum,
    short* __restrict__ Qb, short* __restrict__ Kb, short* __restrict__ Vb,
    short* __restrict__ VbT) {
  constexpr int K = 1024;
  __shared__ __align__(16) short As[128 * 128];   // 32 KB
  __shared__ __align__(16) short Bs[128 * 128];   // 32 KB

  const int tid = threadIdx.x;
  const int wid = tid >> 6, lane = tid & 63;
  const int wm = wid >> 1, wn = wid & 1;   // wave tile 64(m) x 64(n)
  const int lm = lane & 15, quad = lane >> 4;

  const int nt = blockIdx.x;
  const bool isGate = nt < 8;
  const int m0 = blockIdx.y * 128;
  const int n0 = (isGate ? nt : nt - 8) * 128;
  const short* Ag = (const short*)(isGate ? xbf : xn);
  const short* Wg = (const short*)(isGate ? wg : wq);

  f32x4 zero = {0.f, 0.f, 0.f, 0.f};
  f32x4 acc[4][4];
#pragma unroll
  for (int i = 0; i < 4; i++)
#pragma unroll
    for (int j = 0; j < 4; j++) acc[i][j] = zero;

  // staging: per issue, 256 lanes x 16 B = 4 KB = 16 rows x 256 B.
  const int grow = tid >> 4;
  const int swq = ((tid & 15) ^ ((tid >> 4) & 15)) * 8;

  for (int kb = 0; kb < K; kb += 128) {
    __syncthreads();
#pragma unroll
    for (int it = 0; it < 8; it++) {
      const int row = it * 16 + grow;
      gload16(&Ag[(size_t)(m0 + row) * K + kb + swq], &As[it * 2048 + wid * 512]);
      gload16(&Wg[(size_t)(n0 + row) * K + kb + swq], &Bs[it * 2048 + wid * 512]);
    }
    __syncthreads();
#pragma unroll
    for (int sec = 0; sec < 4; sec++) {
      const int slot8 = (((sec * 4 + quad) ^ lm) * 8);
      short8 afr[4], bfr[4];
#pragma unroll
      for (int i = 0; i < 4; i++)
        afr[i] = *(const short8*)&As[(wm * 64 + i * 16 + lm) * 128 + slot8];
#pragma unroll
      for (int j = 0; j < 4; j++)
        bfr[j] = *(const short8*)&Bs[(wn * 64 + j * 16 + lm) * 128 + slot8];
#pragma unroll
      for (int i = 0; i < 4; i++)
#pragma unroll
        for (int j = 0; j < 4; j++)
          acc[i][j] = __builtin_amdgcn_mfma_f32_16x16x32_bf16(afr[i], bfr[j], acc[i][j], 0, 0, 0);
    }
  }

  // epilogue: C/D layout col = lane&15, row = quad*4 + r
  if (isGate) {
    float* red = (float*)As;   // 128 rows x 32 slots = 16 KB (fits in 32 KB As)
    __syncthreads();           // all waves' MFMA LDS reads done -> reuse As
#pragma unroll
    for (int i = 0; i < 4; i++) {
#pragma unroll
      for (int r = 0; r < 4; r++) {
        const int rowl = wm * 64 + i * 16 + quad * 4 + r;
        const int row = m0 + rowl;
        float rp = 0.f;
#pragma unroll
        for (int j = 0; j < 4; j++) {
          const int col = n0 + wn * 64 + j * 16 + lm;
          float v = acc[i][j][r] + gate_b[col];
          float sig = 1.f / (1.f + __expf(-v));
          Gb[(size_t)row * DM + col] = f2b_bits(sig);
          rp += sig;
        }
        red[rowl * 32 + wn * 16 + lm] = rp;
      }
    }
    __syncthreads();
    if (tid < 128) {
      float s = 0.f;
#pragma unroll
      for (int t2 = 0; t2 < 32; t2++) s += red[tid * 32 + t2];
      atomicAdd(&gate_accum[m0 + tid], s);
    }
  } else {
#pragma unroll
    for (int i = 0; i < 4; i++) {
      const int rbase = m0 + wm * 64 + i * 16 + quad * 4;
#pragma unroll
      for (int j = 0; j < 4; j++) {
        const int col = n0 + wn * 64 + j * 16 + lm;
        const float bval = qkv_b[col];
#pragma unroll
        for (int r = 0; r < 4; r++) {
          const int row = rbase + r;
          const short bv = f2b_bits(acc[i][j][r] + bval);
          if (col < DM) {
            const int d = col;
            Qb[((size_t)(d >> 6) * T_SEQ + row) * DH + (d & 63)] = bv;
          } else if (col < 2 * DM) {
            const int d = col - DM;
            Kb[((size_t)(d >> 6) * T_SEQ + row) * DH + (d & 63)] = bv;
          } else {
            const int d = col - 2 * DM;
            Vb[((size_t)(d >> 6) * T_SEQ + row) * DH + (d & 63)] = bv;
            VbT[((size_t)(d >> 6) * DH + (d & 63)) * T_SEQ + row] = bv;
          }
        }
      }
    }
  }
}

// ---------------------------------------------------------------------------
// Pass A: per (h,c) RAW chunk sums, stored TRANSPOSED: SkvT[m][d]. Sk_c = col
// sums of gated K. Gating during staging.
// ---------------------------------------------------------------------------
__global__ __launch_bounds__(256, 2) void chunk_sum_mm(const short* __restrict__ Kb,
                                                       const short* __restrict__ Gb,
                                                       const float* __restrict__ ga,
                                                       const short* __restrict__ Vb,
                                                       float* __restrict__ SkvT,
                                                       float* __restrict__ Sk) {
  constexpr int STR = 68;
  __shared__ __align__(16) float Ks2[64 * STR];
  __shared__ __align__(16) float Vs2[64 * STR];
  const int b = blockIdx.x;
  const int h = b >> 5, c = b & 31;
  const int tid = threadIdx.x;
  const int ty = tid >> 4, tx = tid & 15;
  const int d0 = ty * 4, m0 = tx * 4;
  const int t0 = c * CHUNK;
  const size_t cb = ((size_t)h * T_SEQ + t0) * DH;
#pragma unroll
  for (int p = 0; p < 4; p++) {
    int f = p * 256 + tid, row = f >> 4, seg = (f & 15) * 4;
    const int t = t0 + row;
    short4v kr = *(const short4v*)&Kb[cb + row * 64 + seg];
    short4v gr = *(const short4v*)&Gb[(size_t)t * DM + h * 64 + seg];
    short4v vr = *(const short4v*)&Vb[cb + row * 64 + seg];
    const float inv = 1.f / (ga[t] * (1.f / DM) + 1e-5f);
    f32x4 kgv, vv;
#pragma unroll
    for (int e = 0; e < 4; e++) {
      kgv[e] = gelu1(b2f(kr[e]), b2f(gr[e]), inv);
      vv[e] = b2f(vr[e]);
    }
    *(f32x4*)&Ks2[row * STR + seg] = kgv;
    *(f32x4*)&Vs2[row * STR + seg] = vv;
  }
  __syncthreads();
  float acc[4][4] = {};
#pragma unroll 4
  for (int s = 0; s < 64; s++) {
    f32x4 kf = *(const f32x4*)&Ks2[s * STR + d0];
    f32x4 vf = *(const f32x4*)&Vs2[s * STR + m0];
#pragma unroll
    for (int i = 0; i < 4; i++)
#pragma unroll
      for (int j = 0; j < 4; j++) acc[i][j] += kf[i] * vf[j];
  }
  float* outp = SkvT + (size_t)b * 4096;
  // transposed store: SkvT[m][d] = acc[d][m]
#pragma unroll
  for (int i = 0; i < 4; i++)
#pragma unroll
    for (int j = 0; j < 4; j++)
      outp[(m0 + j) * 64 + (d0 + i)] = acc[i][j];
  if (tid < 64) {
    float ss = 0.f;
#pragma unroll 4
    for (int s = 0; s < 64; s++) ss += Ks2[s * STR + tid];
    Sk[b * 64 + tid] = ss;
  }
}

// ---------------------------------------------------------------------------
// Pass B: exclusive prefix over chunks (elementwise, layout-agnostic).
// ---------------------------------------------------------------------------
__global__ __launch_bounds__(256) void scan_excl(float* __restrict__ Skv,
                                                 float* __restrict__ Sk) {
  const int bid = blockIdx.x, tid = threadIdx.x;
  if (bid < 256) {
    const int id = bid * 256 + tid;
    const int h = id >> 12, e = id & 4095;
    float* base = Skv + (size_t)h * NCHUNK * 4096 + e;
    float v[NCHUNK];
#pragma unroll
    for (int c = 0; c < NCHUNK; c++) v[c] = base[(size_t)c * 4096];
    float run = 0.f;
#pragma unroll
    for (int c = 0; c < NCHUNK; c++) {
      float t = v[c];
      base[(size_t)c * 4096] = run;
      run += t;
    }
  } else {
    const int id = (bid - 256) * 256 + tid;
    const int h = id >> 6, e = id & 63;
    float* base = Sk + (size_t)h * NCHUNK * 64 + e;
    float v[NCHUNK];
#pragma unroll
    for (int c = 0; c < NCHUNK; c++) v[c] = base[c * 64];
    float run = 0.f;
#pragma unroll
    for (int c = 0; c < NCHUNK; c++) {
      float t = v[c];
      base[c * 64] = run;
      run += t;
    }
  }
}

// ---------------------------------------------------------------------------
// Pass C (MFMA): per (h,c), 4 waves.
//   S = Qg.Kg^T; O^T = P^T.Qg^T + V^T.S^T; den from masked-S rowsum + q.skp.
// R13: invden dot product parallelized across all 256 threads.
// ---------------------------------------------------------------------------
__global__ __launch_bounds__(256, 2) void attn_mfma(const short* __restrict__ Qb,
                                                    const short* __restrict__ Kb,
                                                    const short* __restrict__ Gb,
                                                    const float* __restrict__ ga,
                                                    const short* __restrict__ VbT,
                                                    const float* __restrict__ SkvT,
                                                    const float* __restrict__ Sk,
                                                    bf16* __restrict__ O) {
  constexpr int STR = 72;
  __shared__ __align__(16) short Qs[64 * STR];
  __shared__ __align__(16) short Ks[64 * STR];
  __shared__ __align__(16) short Vt[64 * STR];
  __shared__ __align__(16) short Pt[64 * STR];
  __shared__ __align__(16) short SL[64 * STR];
  __shared__ float denp[64], invden[64], skp[64];
  const int b = blockIdx.x;
  const int h = b >> 5, c = b & 31;
  const int tid = threadIdx.x;
  const int wid = tid >> 6, lane = tid & 63;
  const int lm = lane & 15, quad = lane >> 4;
  const int t0 = c * CHUNK;
  const size_t cb = ((size_t)h * T_SEQ + t0) * DH;
  const float* Pg = SkvT + (size_t)b * 4096;

#pragma unroll
  for (int p = 0; p < 4; p++) {
    const int f = p * 256 + tid, row = f >> 4, seg = (f & 15) * 4;
    const int t = t0 + row;
    short4v qr = *(const short4v*)&Qb[cb + row * 64 + seg];
    short4v kr = *(const short4v*)&Kb[cb + row * 64 + seg];
    short4v gr = *(const short4v*)&Gb[(size_t)t * DM + h * 64 + seg];
    short4v vtr = *(const short4v*)&VbT[((size_t)h * DH + row) * T_SEQ + t0 + seg];
    f32x4 pr = *(const f32x4*)&Pg[row * 64 + seg];
    const float inv = 1.f / (ga[t] * (1.f / DM) + 1e-5f);
    short4v qs, ks, ps;
#pragma unroll
    for (int e = 0; e < 4; e++) {
      qs[e] = f2b_bits(gelu1(b2f(qr[e]), b2f(gr[e]), inv));
      ks[e] = f2b_bits(gelu1(b2f(kr[e]), b2f(gr[e]), inv));
      ps[e] = f2b_bits(pr[e]);
    }
    *(short4v*)&Qs[row * STR + seg] = qs;
    *(short4v*)&Ks[row * STR + seg] = ks;
    *(short4v*)&Vt[row * STR + seg] = vtr;
    *(short4v*)&Pt[row * STR + seg] = ps;
  }
  if (tid < 64) skp[tid] = Sk[b * 64 + tid];
  __syncthreads();  // B1

  f32x4 zero = {0.f, 0.f, 0.f, 0.f};
  // ---- S = Qg.Kg^T ----
  short8 aq[2];
#pragma unroll
  for (int ks = 0; ks < 2; ks++)
    aq[ks] = *(const short8*)&Qs[(wid * 16 + lm) * STR + ks * 32 + quad * 8];
  f32x4 accs[4];
#pragma unroll
  for (int j = 0; j < 4; j++) accs[j] = zero;
#pragma unroll
  for (int j = 0; j < 4; j++)
#pragma unroll
    for (int ks = 0; ks < 2; ks++) {
      short8 bk = *(const short8*)&Ks[(j * 16 + lm) * STR + ks * 32 + quad * 8];
      accs[j] = __builtin_amdgcn_mfma_f32_16x16x32_bf16(aq[ks], bk, accs[j], 0, 0, 0);
    }
  float rowpart[4] = {0.f, 0.f, 0.f, 0.f};
#pragma unroll
  for (int j = 0; j < 4; j++) {
    const int s = j * 16 + lm;
#pragma unroll
    for (int r = 0; r < 4; r++) {
      const int t = wid * 16 + quad * 4 + r;
      float v = (s <= t) ? accs[j][r] : 0.f;
      accs[j][r] = v;
      rowpart[r] += v;
    }
  }
#pragma unroll
  for (int msk = 1; msk < 16; msk <<= 1)
#pragma unroll
    for (int r = 0; r < 4; r++) rowpart[r] += __shfl_xor(rowpart[r], msk, 64);
  if (lm == 0)
#pragma unroll
    for (int r = 0; r < 4; r++) denp[wid * 16 + quad * 4 + r] = rowpart[r];
#pragma unroll
  for (int j = 0; j < 4; j++)
#pragma unroll
    for (int r = 0; r < 4; r++)
      SL[(wid * 16 + quad * 4 + r) * STR + j * 16 + lm] = f2b_bits(accs[j][r]);

  // ---- O1^T = P^T.Qg^T ----
  f32x4 acco[4];
#pragma unroll
  for (int j = 0; j < 4; j++) acco[j] = zero;
  short8 ap[2];
#pragma unroll
  for (int ks = 0; ks < 2; ks++)
    ap[ks] = *(const short8*)&Pt[(wid * 16 + lm) * STR + ks * 32 + quad * 8];
#pragma unroll
  for (int j = 0; j < 4; j++)
#pragma unroll
    for (int ks = 0; ks < 2; ks++) {
      short8 bq = *(const short8*)&Qs[(j * 16 + lm) * STR + ks * 32 + quad * 8];
      acco[j] = __builtin_amdgcn_mfma_f32_16x16x32_bf16(ap[ks], bq, acco[j], 0, 0, 0);
    }
  __syncthreads();  // B2: SL + denp complete

  {
    // all 256 threads: row = tid>>2, part = tid&3 covers 16 d each
    const int row = tid >> 2, part = tid & 3;
    float s = 0.f;
#pragma unroll
    for (int dd = 0; dd < 16; dd++) {
      const int d = part * 16 + dd;
      s += b2f(Qs[row * STR + d]) * skp[d];
    }
    s += __shfl_xor(s, 1, 64);
    s += __shfl_xor(s, 2, 64);
    if (part == 0) invden[row] = 1.f / (1e-5f + denp[row] + s);
  }

  // ---- O2^T += V^T.S^T ----
  short8 av[2];
#pragma unroll
  for (int ks = 0; ks < 2; ks++)
    av[ks] = *(const short8*)&Vt[(wid * 16 + lm) * STR + ks * 32 + quad * 8];
#pragma unroll
  for (int j = 0; j < 4; j++)
#pragma unroll
    for (int ks = 0; ks < 2; ks++) {
      short8 bs = *(const short8*)&SL[(j * 16 + lm) * STR + ks * 32 + quad * 8];
      acco[j] = __builtin_amdgcn_mfma_f32_16x16x32_bf16(av[ks], bs, acco[j], 0, 0, 0);
    }
  __syncthreads();  // B3: invden ready

#pragma unroll
  for (int j = 0; j < 4; j++) {
    const int t = j * 16 + lm;
    const float idv = invden[t];
    short4v ov;
#pragma unroll
    for (int r = 0; r < 4; r++) ov[r] = f2b_bits(acco[j][r] * idv);
    *(short4v*)&((short*)O)[(size_t)(t0 + t) * DM + h * 64 + wid * 16 + quad * 4] = ov;
  }
}

// ---------------------------------------------------------------------------
// Proj GEMM: tile 64x64, grid (16 n-fast, 32 m) = 512 blocks (2/CU).
// R24: BK=256 (4 K-steps, was 8) -- same confirmed drain-count lever as
// R23's gateqkv win. LDS 2x32KB = 64 KB; 128 KB/CU at 2 blocks keeps
// residency unchanged (grid-capped at 2/CU anyway).
// Swizzle for 512B rows (32 chunks of 16B): slot s of row r holds chunk
// s^(r&31). Staging: 8 rows/issue, so the XOR is computed per-issue:
// row = it*8 + (tid>>5), source chunk = (tid&31)^(row&31). Read: fragment
// chunk sec*4+quad read from slot (sec*4+quad)^(row&31), row = *16+lm.
// ---------------------------------------------------------------------------
__global__ __launch_bounds__(256) void gemm_proj(const bf16* __restrict__ A,
                                                 const bf16* __restrict__ W,
                                                 const float* __restrict__ bias,
                                                 float* __restrict__ Cout) {
  constexpr int K = 1024;
  __shared__ __align__(16) short As[64 * 256];   // 32 KB
  __shared__ __align__(16) short Bs[64 * 256];   // 32 KB

  const int tid = threadIdx.x;
  const int wid = tid >> 6, lane = tid & 63;
  const int wm = wid >> 1, wn = wid & 1;   // wave tile 32x32
  const int lm = lane & 15, quad = lane >> 4;

  const int n0 = blockIdx.x * 64;
  const int m0 = blockIdx.y * 64;
  const short* Ag = (const short*)A;
  const short* Wg = (const short*)W;

  // staging: per issue, 256 lanes x 16 B = 4 KB = 8 rows x 512 B.
  const int grow = tid >> 5;        // 0..7: row within issue
  const int lchunk = tid & 31;      // LDS slot within row

  f32x4 zero = {0.f, 0.f, 0.f, 0.f};
  f32x4 acc[2][2];
#pragma unroll
  for (int i = 0; i < 2; i++)
#pragma unroll
    for (int j = 0; j < 2; j++) acc[i][j] = zero;

  for (int kb = 0; kb < K; kb += 256) {
    __syncthreads();
#pragma unroll
    for (int it = 0; it < 8; it++) {
      const int row = it * 8 + grow;
      const int swq = (lchunk ^ (row & 31)) * 8;   // source chunk for linear slot
      gload16(&Ag[(size_t)(m0 + row) * K + kb + swq], &As[it * 2048 + wid * 512]);
      gload16(&Wg[(size_t)(n0 + row) * K + kb + swq], &Bs[it * 2048 + wid * 512]);
    }
    __syncthreads();
#pragma unroll
    for (int sec = 0; sec < 8; sec++) {
      short8 afr[2], bfr[2];
#pragma unroll
      for (int i = 0; i < 2; i++) {
        const int row = wm * 32 + i * 16 + lm;
        const int slot8 = (((sec * 4 + quad) ^ (row & 31)) * 8);
        afr[i] = *(const short8*)&As[row * 256 + slot8];
      }
#pragma unroll
      for (int j = 0; j < 2; j++) {
        const int row = wn * 32 + j * 16 + lm;
        const int slot8 = (((sec * 4 + quad) ^ (row & 31)) * 8);
        bfr[j] = *(const short8*)&Bs[row * 256 + slot8];
      }
#pragma unroll
      for (int i = 0; i < 2; i++)
#pragma unroll
        for (int j = 0; j < 2; j++)
          acc[i][j] = __builtin_amdgcn_mfma_f32_16x16x32_bf16(afr[i], bfr[j], acc[i][j], 0, 0, 0);
    }
  }
#pragma unroll
  for (int i = 0; i < 2; i++) {
    const int rbase = m0 + wm * 32 + i * 16 + quad * 4;
#pragma unroll
    for (int j = 0; j < 2; j++) {
      const int col = n0 + wn * 32 + j * 16 + lm;
      const float bval = bias[col];
#pragma unroll
      for (int r = 0; r < 4; r++)
        Cout[(size_t)(rbase + r) * DM + col] = acc[i][j][r] + bval;
    }
  }
}

// ---------------------------------------------------------------------------
extern "C" void kernel_launch(void* const* d_in, const int* in_sizes, int n_in,
                              void* d_out, int out_size, void* d_ws, size_t ws_size,
                              hipStream_t stream) {
  (void)in_sizes; (void)n_in; (void)out_size; (void)ws_size;
  const float* x      = (const float*)d_in[0];
  const float* ln_g   = (const float*)d_in[1];
  const float* ln_b   = (const float*)d_in[2];
  const float* qkv_w  = (const float*)d_in[3];
  const float* qkv_b  = (const float*)d_in[4];
  const float* gate_w = (const float*)d_in[5];
  const float* gate_b = (const float*)d_in[6];
  const float* proj_w = (const float*)d_in[7];
  const float* proj_b = (const float*)d_in[8];
  float* out = (float*)d_out;

  char* ws = (char*)d_ws;
  size_t off = 0;
  auto alloc = [&](size_t bytes) {
    void* p = ws + off;
    off += (bytes + 255) & ~(size_t)255;
    return p;
  };
  bf16*  xn       = (bf16*)alloc((size_t)T_SEQ * DM * 2);
  bf16*  xbf      = (bf16*)alloc((size_t)T_SEQ * DM * 2);
  bf16*  wqkv     = (bf16*)alloc((size_t)3 * DM * DM * 2);
  bf16*  wgate    = (bf16*)alloc((size_t)DM * DM * 2);
  bf16*  wproj    = (bf16*)alloc((size_t)DM * DM * 2);
  short* Gb       = (short*)alloc((size_t)T_SEQ * DM * 2);
  float* gate_accum = (float*)alloc((size_t)T_SEQ * 4);
  short* Qb       = (short*)alloc((size_t)T_SEQ * DM * 2);
  short* Kb       = (short*)alloc((size_t)T_SEQ * DM * 2);
  short* Vb       = (short*)alloc((size_t)T_SEQ * DM * 2);
  short* VbT      = (short*)alloc((size_t)T_SEQ * DM * 2);
  bf16*  Obuf     = (bf16*)alloc((size_t)T_SEQ * DM * 2);
  float* SkvT     = (float*)alloc((size_t)NH * NCHUNK * 4096 * 4);
  float* Sk       = (float*)alloc((size_t)NH * NCHUNK * 64 * 4);

  prep_kernel<<<T_SEQ + PREP_WBLOCKS, 256, 0, stream>>>(
      x, ln_g, ln_b, qkv_w, gate_w, proj_w, xn, xbf, wqkv, wgate, wproj, gate_accum);
  gemm_gateqkv<<<dim3(32, 16), 256, 0, stream>>>(xbf, xn, wgate, wqkv, gate_b, qkv_b,
                                                 Gb, gate_accum, Qb, Kb, Vb, VbT);
  chunk_sum_mm<<<NH * NCHUNK, 256, 0, stream>>>(Kb, Gb, gate_accum, Vb, SkvT, Sk);
  scan_excl<<<260, 256, 0, stream>>>(SkvT, Sk);
  attn_mfma<<<NH * NCHUNK, 256, 0, stream>>>(Qb, Kb, Gb, gate_accum, VbT, SkvT, Sk, Obuf);
  gemm_proj<<<dim3(16, 32), 256, 0, stream>>>(Obuf, wproj, proj_b, out);
}